// Round 1
// 479.780 us; speedup vs baseline: 1.0272x; 1.0272x over previous
//
#include <hip/hip_runtime.h>
#include <hip/hip_bf16.h>

// Problem constants (HumanVAttention: B=2,T=4096,HID=2048,H=16,HKV=4,D=128,
// ROT=64, BLK=64, LOCAL=8, GLOB=1).
// DTYPE (established empirically): harness presents ALL tensors in f32.
// Internal compute bf16 MFMA; I/O f32. Threshold is bf16-grade.
#define Hq   16
#define HKV  4
#define Dh   128
#define ROT  64
#define BLKQ 64
#define NBLK 64      // T/BLK
#define Tlen 4096
#define Bsz  2
#define HID  2048
#define QKVC 3072    // 2048 q + 512 k + 512 v
#define SCALE_C 0.08838834764831845f

typedef __attribute__((ext_vector_type(8))) short bf16x8;
typedef __attribute__((ext_vector_type(4))) float f32x4;

#define MFMA16(a, b, c) __builtin_amdgcn_mfma_f32_16x16x32_bf16((a), (b), (c), 0, 0, 0)

__device__ __forceinline__ void async_copy16(__hip_bfloat16* lds, const __hip_bfloat16* g) {
    __builtin_amdgcn_global_load_lds(
        (const __attribute__((address_space(1))) void*)g,
        (__attribute__((address_space(3))) void*)lds,
        16, 0, 0);
}

// f32 -> bf16 bulk convert. blockIdx.y selects tensor {hs, Wq, Wk, Wv, Wo}.
__global__ __launch_bounds__(256) void cvt_kernel(
    const float* __restrict__ s0, const float* __restrict__ s1,
    const float* __restrict__ s2, const float* __restrict__ s3,
    const float* __restrict__ s4,
    __hip_bfloat16* __restrict__ base,
    int n0, int n1, int n2, int n3, int n4)
{
    const float* src;
    size_t off, n;
    switch (blockIdx.y) {
        case 0:  src = s0; off = 0;                          n = n0; break;
        case 1:  src = s1; off = (size_t)n0;                 n = n1; break;
        case 2:  src = s2; off = (size_t)n0 + n1;            n = n2; break;
        case 3:  src = s3; off = (size_t)n0 + n1 + n2;       n = n3; break;
        default: src = s4; off = (size_t)n0 + n1 + n2 + n3;  n = n4; break;
    }
    __hip_bfloat16* dst = base + off;
    const size_t stride = (size_t)gridDim.x * 2048;
    for (size_t i = ((size_t)blockIdx.x * 256 + threadIdx.x) * 8; i < n; i += stride) {
        const float4 a = *(const float4*)(src + i);
        const float4 b = *(const float4*)(src + i + 4);
        union { bf16x8 v; __hip_bfloat16 e[8]; } u;
        u.e[0] = __float2bfloat16(a.x); u.e[1] = __float2bfloat16(a.y);
        u.e[2] = __float2bfloat16(a.z); u.e[3] = __float2bfloat16(a.w);
        u.e[4] = __float2bfloat16(b.x); u.e[5] = __float2bfloat16(b.y);
        u.e[6] = __float2bfloat16(b.z); u.e[7] = __float2bfloat16(b.w);
        *(bf16x8*)(dst + i) = u.v;
    }
}

// C[M,N] = A[M,K] * B[N,K]^T, bf16 in, 256x256 tile, BK=64, 8 waves (2Mx4N),
// 512 threads, 128 KiB LDS double-buffer. 8-phase-per-2-K-tiles schedule
// (T3+T4 counted vmcnt + T5 setprio), per guide's 256sq template.
//
// Schedule invariants (tile u, parity P=u&1, 4 phases per K-tile):
//   p1: ds_read k0 frags (12 b128); stage Bh0(u+1)->bufB[P^1]; bar; lgkm0;
//       MFMA Q1 (k0, n0-1)
//   p2: ds_read k1 A-frags (8);     stage Bh1(u+1)->bufB[P^1]; bar;
//       MFMA Q2 (k0, n2-3)
//   p3: ds_read k1 B-frags (4);     bar; lgkm0;  MFMA Q3 (k1, n0-1)
//       (lgkm0 here => ALL bufA[P]/bufB[P] reads in regs before p4 stage)
//   p4: stage Ah0+Ah1(u+2)->bufA[P]; vmcnt(4); bar;  MFMA Q4 (k1, n2-3)
// Read coverage: tile v's A staged at (v-2).p4, B at (v-1).p1/p2; the
// vmcnt(4) at (v-1).p4 leaves only A(v+1)'s 4 loads in flight => all of
// tile v complete before v.p1 (per-wave vmcnt + barrier = cross-wave safe).
// Write safety: bufB[P^1] last read (u-1).p1/p3 (lgkm'd); bufA[P] tile-u
// reads done by p3's lgkm0; barriers separate.
template <bool ROPE_, bool F32OUT>
__global__ __launch_bounds__(512) void gemm256(
    const __hip_bfloat16* __restrict__ A,
    const __hip_bfloat16* __restrict__ B0,
    const __hip_bfloat16* __restrict__ B1,
    const __hip_bfloat16* __restrict__ B2,
    int n1c, int n2c,
    void* __restrict__ C,
    int M, int N, int K,
    const float* __restrict__ cosb,
    const float* __restrict__ sinb)
{
    __shared__ __align__(16) __hip_bfloat16 As[2][256 * 64];
    __shared__ __align__(16) __hip_bfloat16 Bs[2][256 * 64];

    // XCD-aware bijective swizzle (nwg % 8 == 0 for both call sites).
    const int gn  = N >> 8;
    const int nwg = (M >> 8) * gn;
    const int id  = blockIdx.x;
    const int swz = (id & 7) * (nwg >> 3) + (id >> 3);
    const int mt  = swz / gn;
    const int nt  = swz - mt * gn;
    const int m0  = mt << 8;
    const int n0  = nt << 8;

    const __hip_bfloat16* Bp;
    int nb;
    if (n0 < n1c)      { Bp = B0; nb = n0; }
    else if (n0 < n2c) { Bp = B1; nb = n0 - n1c; }
    else               { Bp = B2; nb = n0 - n2c; }

    const int tid  = threadIdx.x;
    const int lane = tid & 63;
    const int w    = tid >> 6;            // wave 0..7
    const int wm   = (w >> 2) << 7;       // 0 / 128
    const int wn   = (w & 3) << 6;        // 0 / 64 / 128 / 192
    const int m16  = lane & 15;
    const int q8   = lane >> 4;
    const int lr   = lane >> 3;           // staging row-in-group 0..7
    const int lc   = lane & 7;            // staging chunk slot
    const int cg   = lc ^ lr;             // pre-swizzled global chunk (row&7==lr)
    const int NT   = K >> 6;              // K-tiles (>=2, even)

    f32x4 acc[8][4] = {};

    // Stage one 128-row half of A/B tile: 2 x global_load_lds per thread.
    // LDS linear dest (wave-uniform base + lane*16B); swizzle via source.
    auto stageA = [&](int buf, int half, int kc) {
        #pragma unroll
        for (int is = 0; is < 2; ++is) {
            const int r8 = (half << 7) + (is << 6) + (w << 3);
            async_copy16(&As[buf][r8 << 6],
                         A + (size_t)(m0 + r8 + lr) * K + kc + (cg << 3));
        }
    };
    auto stageB = [&](int buf, int half, int kc) {
        #pragma unroll
        for (int is = 0; is < 2; ++is) {
            const int r8 = (half << 7) + (is << 6) + (w << 3);
            async_copy16(&Bs[buf][r8 << 6],
                         Bp + (size_t)(nb + r8 + lr) * K + kc + (cg << 3));
        }
    };

    // Prologue: A(0), B(0) -> buf0; A(1) -> buf1; wait all but A(1).
    stageA(0, 0, 0);  stageA(0, 1, 0);
    stageB(0, 0, 0);  stageB(0, 1, 0);
    stageA(1, 0, 64); stageA(1, 1, 64);
    asm volatile("s_waitcnt vmcnt(4)" ::: "memory");
    __builtin_amdgcn_s_barrier();

    for (int u = 0; u < NT; ++u) {
        const int P = u & 1;
        int tB = u + 1; if (tB >= NT) tB -= NT;
        int tA = u + 2; if (tA >= NT) tA -= NT;
        const int kB = tB << 6;
        const int kA = tA << 6;
        const __hip_bfloat16* Ap_ = As[P];
        const __hip_bfloat16* Bq_ = Bs[P];
        const int csl = m16 & 7;          // row&7 for all frag rows

        bf16x8 a0[8], b0[4], a1[8], b1[4];

        // ---- phase 1: k0 frags + stage Bh0(u+1)
        #pragma unroll
        for (int m = 0; m < 8; ++m) {
            const int row = wm + (m << 4) + m16;
            const int cs  = q8 ^ csl;
            a0[m] = *(const bf16x8*)&Ap_[(row << 6) + (cs << 3)];
        }
        #pragma unroll
        for (int n = 0; n < 4; ++n) {
            const int row = wn + (n << 4) + m16;
            const int cs  = q8 ^ csl;
            b0[n] = *(const bf16x8*)&Bq_[(row << 6) + (cs << 3)];
        }
        stageB(P ^ 1, 0, kB);
        __builtin_amdgcn_s_barrier();
        asm volatile("s_waitcnt lgkmcnt(0)" ::: "memory");
        __builtin_amdgcn_s_setprio(1);
        #pragma unroll
        for (int m = 0; m < 8; ++m) {
            acc[m][0] = MFMA16(a0[m], b0[0], acc[m][0]);
            acc[m][1] = MFMA16(a0[m], b0[1], acc[m][1]);
        }
        __builtin_amdgcn_s_setprio(0);
        __builtin_amdgcn_s_barrier();

        // ---- phase 2: k1 A-frags + stage Bh1(u+1)
        #pragma unroll
        for (int m = 0; m < 8; ++m) {
            const int row = wm + (m << 4) + m16;
            const int cs  = (4 + q8) ^ csl;
            a1[m] = *(const bf16x8*)&Ap_[(row << 6) + (cs << 3)];
        }
        stageB(P ^ 1, 1, kB);
        __builtin_amdgcn_s_barrier();
        __builtin_amdgcn_s_setprio(1);
        #pragma unroll
        for (int m = 0; m < 8; ++m) {
            acc[m][2] = MFMA16(a0[m], b0[2], acc[m][2]);
            acc[m][3] = MFMA16(a0[m], b0[3], acc[m][3]);
        }
        __builtin_amdgcn_s_setprio(0);
        __builtin_amdgcn_s_barrier();

        // ---- phase 3: k1 B-frags
        #pragma unroll
        for (int n = 0; n < 4; ++n) {
            const int row = wn + (n << 4) + m16;
            const int cs  = (4 + q8) ^ csl;
            b1[n] = *(const bf16x8*)&Bq_[(row << 6) + (cs << 3)];
        }
        __builtin_amdgcn_s_barrier();
        asm volatile("s_waitcnt lgkmcnt(0)" ::: "memory");   // all buf[P] reads in regs
        __builtin_amdgcn_s_setprio(1);
        #pragma unroll
        for (int m = 0; m < 8; ++m) {
            acc[m][0] = MFMA16(a1[m], b1[0], acc[m][0]);
            acc[m][1] = MFMA16(a1[m], b1[1], acc[m][1]);
        }
        __builtin_amdgcn_s_setprio(0);
        __builtin_amdgcn_s_barrier();

        // ---- phase 4: stage Ah0+Ah1(u+2) into bufA[P]; counted vmcnt
        stageA(P, 0, kA);
        stageA(P, 1, kA);
        asm volatile("s_waitcnt vmcnt(4)" ::: "memory");
        __builtin_amdgcn_s_barrier();
        __builtin_amdgcn_s_setprio(1);
        #pragma unroll
        for (int m = 0; m < 8; ++m) {
            acc[m][2] = MFMA16(a1[m], b1[2], acc[m][2]);
            acc[m][3] = MFMA16(a1[m], b1[3], acc[m][3]);
        }
        __builtin_amdgcn_s_setprio(0);
        __builtin_amdgcn_s_barrier();
    }

    // Fused RoPE: wave covers 64 consecutive cols; rotary iff head-col base 0
    // and q/k head (col < 2560). Pairs (d, d+32) = n-frags (j, j+2), j in {0,1}.
    const int c0 = n0 + wn;
    if (ROPE_ && c0 < n2c && (c0 & 64) == 0) {
        #pragma unroll
        for (int i = 0; i < 8; ++i)
            #pragma unroll
            for (int r = 0; r < 4; ++r) {
                const int bt = m0 + wm + (i << 4) + (q8 << 2) + r;   // b*T + t
                #pragma unroll
                for (int j = 0; j < 2; ++j) {
                    const int d = (j << 4) + m16;
                    const float c = cosb[(size_t)bt * ROT + d];
                    const float s = sinb[(size_t)bt * ROT + d];
                    const float x1 = acc[i][j][r];
                    const float x2 = acc[i][j + 2][r];
                    acc[i][j][r]     = x1 * c - x2 * s;
                    acc[i][j + 2][r] = x2 * c + x1 * s;
                }
            }
    }

    // epilogue: C layout col=lane&15, row=(lane>>4)*4+reg
    #pragma unroll
    for (int i = 0; i < 8; ++i)
        #pragma unroll
        for (int j = 0; j < 4; ++j)
            #pragma unroll
            for (int r = 0; r < 4; ++r) {
                const int row = m0 + wm + (i << 4) + (q8 << 2) + r;
                const int col = n0 + wn + (j << 4) + m16;
                if (F32OUT)
                    ((float*)C)[(size_t)row * N + col] = acc[i][j][r];
                else
                    ((__hip_bfloat16*)C)[(size_t)row * N + col] =
                        __float2bfloat16(acc[i][j][r]);
            }
}

// Block-sparse flash attention (unchanged, harness-verified).
__global__ __launch_bounds__(256) void attn_kernel(
    const __hip_bfloat16* __restrict__ qkv,
    __hip_bfloat16* __restrict__ outb)
{
    const int i   = blockIdx.x;   // q block
    const int h   = blockIdx.y;
    const int b   = blockIdx.z;
    const int kvh = h >> 2;
    const int tid  = threadIdx.x;
    const int lane = tid & 63;
    const int w    = tid >> 6;
    const int m16  = lane & 15;
    const int q8   = lane >> 4;

    __shared__ __align__(16) __hip_bfloat16 Ks[64 * 136];
    __shared__ __align__(16) __hip_bfloat16 VT[128 * 72];
    __shared__ __align__(16) __hip_bfloat16 Pb[4][16 * 72];

    bf16x8 qf[4];
    {
        const __hip_bfloat16* qp =
            qkv + (size_t)(b * Tlen + i * BLKQ + w * 16 + m16) * QKVC + h * Dh + q8 * 8;
        for (int ks = 0; ks < 4; ++ks) qf[ks] = *(const bf16x8*)(qp + ks * 32);
    }

    f32x4 o[8] = {};
    float mrow[4] = {-1e30f, -1e30f, -1e30f, -1e30f};
    float lrow[4] = {0.f, 0.f, 0.f, 0.f};

    const int nsel = (i + 1 < 9) ? (i + 1) : 9;
    for (int j = 0; j < nsel; ++j) {
        const int kb = (i <= 7) ? j : ((j == 0) ? 0 : (i - 8 + j));

        __syncthreads();
        {
            const __hip_bfloat16* kbase =
                qkv + (size_t)(b * Tlen + kb * BLKQ) * QKVC + HID + kvh * Dh;
            const __hip_bfloat16* vbase = kbase + 512;
            for (int c = tid; c < 1024; c += 256) {
                const int key = c >> 4;
                const int d0  = (c & 15) * 8;
                *(bf16x8*)&Ks[key * 136 + d0] =
                    *(const bf16x8*)(kbase + (size_t)key * QKVC + d0);
            }
            for (int c = tid; c < 1024; c += 256) {
                const int key = c & 63;
                const int d0  = (c >> 6) * 8;
                bf16x8 v8 = *(const bf16x8*)(vbase + (size_t)key * QKVC + d0);
                const __hip_bfloat16* ve = (const __hip_bfloat16*)&v8;
                for (int jj = 0; jj < 8; ++jj)
                    VT[(d0 + jj) * 72 + key] = ve[jj];
            }
        }
        __syncthreads();

        float sv[4][4];
        for (int nt = 0; nt < 4; ++nt) {
            f32x4 s = {0.f, 0.f, 0.f, 0.f};
            for (int ks = 0; ks < 4; ++ks) {
                bf16x8 kf = *(const bf16x8*)&Ks[(nt * 16 + m16) * 136 + ks * 32 + q8 * 8];
                s = MFMA16(qf[ks], kf, s);
            }
            for (int r = 0; r < 4; ++r) sv[nt][r] = s[r] * SCALE_C;
        }
        if (kb == i) {
            for (int nt = 0; nt < 4; ++nt) {
                const int key = nt * 16 + m16;
                for (int r = 0; r < 4; ++r) {
                    const int qr = w * 16 + q8 * 4 + r;
                    if (key > qr) sv[nt][r] = -1e9f;
                }
            }
        }

        float alpha[4];
        for (int r = 0; r < 4; ++r) {
            float mx = fmaxf(fmaxf(sv[0][r], sv[1][r]), fmaxf(sv[2][r], sv[3][r]));
            for (int off = 1; off < 16; off <<= 1) mx = fmaxf(mx, __shfl_xor(mx, off, 64));
            const float newm = fmaxf(mrow[r], mx);
            alpha[r] = __expf(mrow[r] - newm);
            mrow[r] = newm;
            float rs = 0.f;
            for (int nt = 0; nt < 4; ++nt) {
                const float p = __expf(sv[nt][r] - newm);
                sv[nt][r] = p;
                rs += p;
            }
            for (int off = 1; off < 16; off <<= 1) rs += __shfl_xor(rs, off, 64);
            lrow[r] = lrow[r] * alpha[r] + rs;
        }

        __hip_bfloat16* Pw = &Pb[w][0];
        for (int nt = 0; nt < 4; ++nt)
            for (int r = 0; r < 4; ++r)
                Pw[(q8 * 4 + r) * 72 + nt * 16 + m16] = __float2bfloat16(sv[nt][r]);

        for (int dt = 0; dt < 8; ++dt)
            for (int r = 0; r < 4; ++r)
                o[dt][r] *= alpha[r];

        __syncthreads();

        for (int kk = 0; kk < 2; ++kk) {
            bf16x8 pf = *(const bf16x8*)&Pw[m16 * 72 + kk * 32 + q8 * 8];
            for (int dt = 0; dt < 8; ++dt) {
                bf16x8 vf = *(const bf16x8*)&VT[(dt * 16 + m16) * 72 + kk * 32 + q8 * 8];
                o[dt] = MFMA16(pf, vf, o[dt]);
            }
        }
    }

    float rcp[4];
    for (int r = 0; r < 4; ++r) rcp[r] = 1.0f / lrow[r];
    __hip_bfloat16* op = outb + (size_t)(b * Tlen + i * BLKQ) * (Hq * Dh) + h * Dh;
    for (int dt = 0; dt < 8; ++dt)
        for (int r = 0; r < 4; ++r) {
            const float val = o[dt][r] * rcp[r];
            op[(size_t)(w * 16 + q8 * 4 + r) * (Hq * Dh) + dt * 16 + m16] =
                __float2bfloat16(val);
        }
}

extern "C" void kernel_launch(void* const* d_in, const int* in_sizes, int n_in,
                              void* d_out, int out_size, void* d_ws, size_t ws_size,
                              hipStream_t stream) {
    const float* hs   = (const float*)d_in[0];
    const float* cosb = (const float*)d_in[1];
    const float* sinb = (const float*)d_in[2];
    const float* Wq   = (const float*)d_in[3];
    const float* Wk   = (const float*)d_in[4];
    const float* Wv   = (const float*)d_in[5];
    const float* Wo   = (const float*)d_in[6];

    const int M = Bsz * Tlen;                 // 8192
    const int nHS = M * HID;
    const int nWq = Hq * Dh * HID;
    const int nWk = HKV * Dh * HID;
    const int nWv = nWk;
    const int nWo = HID * Hq * Dh;

    __hip_bfloat16* hsb  = (__hip_bfloat16*)d_ws;
    __hip_bfloat16* wqb  = hsb + nHS;
    __hip_bfloat16* wkb  = wqb + nWq;
    __hip_bfloat16* wvb  = wkb + nWk;
    __hip_bfloat16* wob  = wvb + nWv;
    __hip_bfloat16* qkv  = wob + nWo;               // [8192][3072]
    __hip_bfloat16* attn = qkv + (size_t)M * QKVC;  // [8192][2048]

    // 0) f32 -> bf16 conversion of hs + all weights
    cvt_kernel<<<dim3(8192, 5), 256, 0, stream>>>(
        hs, Wq, Wk, Wv, Wo, hsb, nHS, nWq, nWk, nWv, nWo);
    // 1) fused QKV projection + RoPE epilogue (bf16 out), 256sq 8-phase
    gemm256<true, false><<<dim3((QKVC / 256) * (M / 256)), 512, 0, stream>>>(
        hsb, wqb, wkb, wvb, HID, HID + 512, qkv, M, QKVC, HID, cosb, sinb);
    // 2) block-sparse attention (bf16)
    attn_kernel<<<dim3(NBLK, Hq, Bsz), 256, 0, stream>>>(qkv, attn);
    // 3) output projection (f32 out to d_out), 256sq 8-phase
    gemm256<false, true><<<dim3((HID / 256) * (M / 256)), 512, 0, stream>>>(
        attn, wob, wob, wob, HID, HID, d_out, M, HID, HID, nullptr, nullptr);
}

// Round 2
// 450.788 us; speedup vs baseline: 1.0932x; 1.0643x over previous
//
#include <hip/hip_runtime.h>
#include <hip/hip_bf16.h>

// Problem constants (HumanVAttention: B=2,T=4096,HID=2048,H=16,HKV=4,D=128,
// ROT=64, BLK=64, LOCAL=8, GLOB=1).
// DTYPE (established empirically): harness presents ALL tensors in f32.
// Internal compute bf16 MFMA; I/O f32. Threshold is bf16-grade.
#define Hq   16
#define HKV  4
#define Dh   128
#define ROT  64
#define BLKQ 64
#define NBLK 64      // T/BLK
#define Tlen 4096
#define Bsz  2
#define HID  2048
#define QKVC 3072    // 2048 q + 512 k + 512 v
#define SCALE_C 0.08838834764831845f

typedef __attribute__((ext_vector_type(8))) short bf16x8;
typedef __attribute__((ext_vector_type(4))) float f32x4;

#define MFMA16(a, b, c) __builtin_amdgcn_mfma_f32_16x16x32_bf16((a), (b), (c), 0, 0, 0)

__device__ __forceinline__ void async_copy16(__hip_bfloat16* lds, const __hip_bfloat16* g) {
    __builtin_amdgcn_global_load_lds(
        (const __attribute__((address_space(1))) void*)g,
        (__attribute__((address_space(3))) void*)lds,
        16, 0, 0);
}

// f32 -> bf16 bulk convert. blockIdx.y selects tensor {hs, Wq, Wk, Wv, Wo}.
__global__ __launch_bounds__(256) void cvt_kernel(
    const float* __restrict__ s0, const float* __restrict__ s1,
    const float* __restrict__ s2, const float* __restrict__ s3,
    const float* __restrict__ s4,
    __hip_bfloat16* __restrict__ base,
    int n0, int n1, int n2, int n3, int n4)
{
    const float* src;
    size_t off, n;
    switch (blockIdx.y) {
        case 0:  src = s0; off = 0;                          n = n0; break;
        case 1:  src = s1; off = (size_t)n0;                 n = n1; break;
        case 2:  src = s2; off = (size_t)n0 + n1;            n = n2; break;
        case 3:  src = s3; off = (size_t)n0 + n1 + n2;       n = n3; break;
        default: src = s4; off = (size_t)n0 + n1 + n2 + n3;  n = n4; break;
    }
    __hip_bfloat16* dst = base + off;
    const size_t stride = (size_t)gridDim.x * 2048;
    for (size_t i = ((size_t)blockIdx.x * 256 + threadIdx.x) * 8; i < n; i += stride) {
        const float4 a = *(const float4*)(src + i);
        const float4 b = *(const float4*)(src + i + 4);
        union { bf16x8 v; __hip_bfloat16 e[8]; } u;
        u.e[0] = __float2bfloat16(a.x); u.e[1] = __float2bfloat16(a.y);
        u.e[2] = __float2bfloat16(a.z); u.e[3] = __float2bfloat16(a.w);
        u.e[4] = __float2bfloat16(b.x); u.e[5] = __float2bfloat16(b.y);
        u.e[6] = __float2bfloat16(b.z); u.e[7] = __float2bfloat16(b.w);
        *(bf16x8*)(dst + i) = u.v;
    }
}

// C[M,N] = A[M,K] * B[N,K]^T, bf16 in, 256x256 tile, BK=64, 8 waves (2Mx4N),
// 512 threads, 128 KiB LDS double-buffer, 4-phase counted-vmcnt schedule.
// ROUND-2 CHANGE: __launch_bounds__(512, 2). LDS (128 KiB) already caps
// occupancy at 1 block = 2 waves/EU; without the min-waves hint the compiler
// targeted higher occupancy and capped unified regs at 128 (measured
// VGPR_Count=128 vs ~250 live) -> spill/pressure-serialization suspect for
// the flat 146us. 2 waves/EU legitimizes a 256-reg budget.
//
// Schedule invariants (tile u, parity P=u&1, 4 phases per K-tile):
//   p1: ds_read k0 frags (12 b128); stage Bh0(u+1)->bufB[P^1]; bar; lgkm0;
//       MFMA Q1 (k0, n0-1)
//   p2: ds_read k1 A-frags (8);     stage Bh1(u+1)->bufB[P^1]; bar;
//       MFMA Q2 (k0, n2-3)
//   p3: ds_read k1 B-frags (4);     bar; lgkm0;  MFMA Q3 (k1, n0-1)
//   p4: stage Ah0+Ah1(u+2)->bufA[P]; vmcnt(4); bar;  MFMA Q4 (k1, n2-3)
template <bool ROPE_, bool F32OUT>
__global__ __launch_bounds__(512, 2) void gemm256(
    const __hip_bfloat16* __restrict__ A,
    const __hip_bfloat16* __restrict__ B0,
    const __hip_bfloat16* __restrict__ B1,
    const __hip_bfloat16* __restrict__ B2,
    int n1c, int n2c,
    void* __restrict__ C,
    int M, int N, int K,
    const float* __restrict__ cosb,
    const float* __restrict__ sinb)
{
    __shared__ __align__(16) __hip_bfloat16 As[2][256 * 64];
    __shared__ __align__(16) __hip_bfloat16 Bs[2][256 * 64];

    // XCD-aware bijective swizzle (nwg % 8 == 0 for both call sites).
    const int gn  = N >> 8;
    const int nwg = (M >> 8) * gn;
    const int id  = blockIdx.x;
    const int swz = (id & 7) * (nwg >> 3) + (id >> 3);
    const int mt  = swz / gn;
    const int nt  = swz - mt * gn;
    const int m0  = mt << 8;
    const int n0  = nt << 8;

    const __hip_bfloat16* Bp;
    int nb;
    if (n0 < n1c)      { Bp = B0; nb = n0; }
    else if (n0 < n2c) { Bp = B1; nb = n0 - n1c; }
    else               { Bp = B2; nb = n0 - n2c; }

    const int tid  = threadIdx.x;
    const int lane = tid & 63;
    const int w    = tid >> 6;            // wave 0..7
    const int wm   = (w >> 2) << 7;       // 0 / 128
    const int wn   = (w & 3) << 6;        // 0 / 64 / 128 / 192
    const int m16  = lane & 15;
    const int q8   = lane >> 4;
    const int lr   = lane >> 3;           // staging row-in-group 0..7
    const int lc   = lane & 7;            // staging chunk slot
    const int cg   = lc ^ lr;             // pre-swizzled global chunk (row&7==lr)
    const int NT   = K >> 6;              // K-tiles (>=2, even)

    f32x4 acc[8][4] = {};

    auto stageA = [&](int buf, int half, int kc) {
        #pragma unroll
        for (int is = 0; is < 2; ++is) {
            const int r8 = (half << 7) + (is << 6) + (w << 3);
            async_copy16(&As[buf][r8 << 6],
                         A + (size_t)(m0 + r8 + lr) * K + kc + (cg << 3));
        }
    };
    auto stageB = [&](int buf, int half, int kc) {
        #pragma unroll
        for (int is = 0; is < 2; ++is) {
            const int r8 = (half << 7) + (is << 6) + (w << 3);
            async_copy16(&Bs[buf][r8 << 6],
                         Bp + (size_t)(nb + r8 + lr) * K + kc + (cg << 3));
        }
    };

    // Prologue: A(0), B(0) -> buf0; A(1) -> buf1; wait all but A(1).
    stageA(0, 0, 0);  stageA(0, 1, 0);
    stageB(0, 0, 0);  stageB(0, 1, 0);
    stageA(1, 0, 64); stageA(1, 1, 64);
    asm volatile("s_waitcnt vmcnt(4)" ::: "memory");
    __builtin_amdgcn_s_barrier();

    for (int u = 0; u < NT; ++u) {
        const int P = u & 1;
        int tB = u + 1; if (tB >= NT) tB -= NT;
        int tA = u + 2; if (tA >= NT) tA -= NT;
        const int kB = tB << 6;
        const int kA = tA << 6;
        const __hip_bfloat16* Ap_ = As[P];
        const __hip_bfloat16* Bq_ = Bs[P];
        const int csl = m16 & 7;          // row&7 for all frag rows

        bf16x8 a0[8], b0[4], a1[8], b1[4];

        // ---- phase 1: k0 frags + stage Bh0(u+1)
        #pragma unroll
        for (int m = 0; m < 8; ++m) {
            const int row = wm + (m << 4) + m16;
            const int cs  = q8 ^ csl;
            a0[m] = *(const bf16x8*)&Ap_[(row << 6) + (cs << 3)];
        }
        #pragma unroll
        for (int n = 0; n < 4; ++n) {
            const int row = wn + (n << 4) + m16;
            const int cs  = q8 ^ csl;
            b0[n] = *(const bf16x8*)&Bq_[(row << 6) + (cs << 3)];
        }
        stageB(P ^ 1, 0, kB);
        __builtin_amdgcn_s_barrier();
        asm volatile("s_waitcnt lgkmcnt(0)" ::: "memory");
        __builtin_amdgcn_s_setprio(1);
        #pragma unroll
        for (int m = 0; m < 8; ++m) {
            acc[m][0] = MFMA16(a0[m], b0[0], acc[m][0]);
            acc[m][1] = MFMA16(a0[m], b0[1], acc[m][1]);
        }
        __builtin_amdgcn_s_setprio(0);
        __builtin_amdgcn_s_barrier();

        // ---- phase 2: k1 A-frags + stage Bh1(u+1)
        #pragma unroll
        for (int m = 0; m < 8; ++m) {
            const int row = wm + (m << 4) + m16;
            const int cs  = (4 + q8) ^ csl;
            a1[m] = *(const bf16x8*)&Ap_[(row << 6) + (cs << 3)];
        }
        stageB(P ^ 1, 1, kB);
        __builtin_amdgcn_s_barrier();
        __builtin_amdgcn_s_setprio(1);
        #pragma unroll
        for (int m = 0; m < 8; ++m) {
            acc[m][2] = MFMA16(a0[m], b0[2], acc[m][2]);
            acc[m][3] = MFMA16(a0[m], b0[3], acc[m][3]);
        }
        __builtin_amdgcn_s_setprio(0);
        __builtin_amdgcn_s_barrier();

        // ---- phase 3: k1 B-frags
        #pragma unroll
        for (int n = 0; n < 4; ++n) {
            const int row = wn + (n << 4) + m16;
            const int cs  = (4 + q8) ^ csl;
            b1[n] = *(const bf16x8*)&Bq_[(row << 6) + (cs << 3)];
        }
        __builtin_amdgcn_s_barrier();
        asm volatile("s_waitcnt lgkmcnt(0)" ::: "memory");   // all buf[P] reads in regs
        __builtin_amdgcn_s_setprio(1);
        #pragma unroll
        for (int m = 0; m < 8; ++m) {
            acc[m][0] = MFMA16(a1[m], b1[0], acc[m][0]);
            acc[m][1] = MFMA16(a1[m], b1[1], acc[m][1]);
        }
        __builtin_amdgcn_s_setprio(0);
        __builtin_amdgcn_s_barrier();

        // ---- phase 4: stage Ah0+Ah1(u+2) into bufA[P]; counted vmcnt
        stageA(P, 0, kA);
        stageA(P, 1, kA);
        asm volatile("s_waitcnt vmcnt(4)" ::: "memory");
        __builtin_amdgcn_s_barrier();
        __builtin_amdgcn_s_setprio(1);
        #pragma unroll
        for (int m = 0; m < 8; ++m) {
            acc[m][2] = MFMA16(a1[m], b1[2], acc[m][2]);
            acc[m][3] = MFMA16(a1[m], b1[3], acc[m][3]);
        }
        __builtin_amdgcn_s_setprio(0);
        __builtin_amdgcn_s_barrier();
    }

    // Fused RoPE: wave covers 64 consecutive cols; rotary iff head-col base 0
    // and q/k head (col < 2560). Pairs (d, d+32) = n-frags (j, j+2), j in {0,1}.
    const int c0 = n0 + wn;
    if (ROPE_ && c0 < n2c && (c0 & 64) == 0) {
        #pragma unroll
        for (int i = 0; i < 8; ++i)
            #pragma unroll
            for (int r = 0; r < 4; ++r) {
                const int bt = m0 + wm + (i << 4) + (q8 << 2) + r;   // b*T + t
                #pragma unroll
                for (int j = 0; j < 2; ++j) {
                    const int d = (j << 4) + m16;
                    const float c = cosb[(size_t)bt * ROT + d];
                    const float s = sinb[(size_t)bt * ROT + d];
                    const float x1 = acc[i][j][r];
                    const float x2 = acc[i][j + 2][r];
                    acc[i][j][r]     = x1 * c - x2 * s;
                    acc[i][j + 2][r] = x2 * c + x1 * s;
                }
            }
    }

    // epilogue: C layout col=lane&15, row=(lane>>4)*4+reg
    #pragma unroll
    for (int i = 0; i < 8; ++i)
        #pragma unroll
        for (int j = 0; j < 4; ++j)
            #pragma unroll
            for (int r = 0; r < 4; ++r) {
                const int row = m0 + wm + (i << 4) + (q8 << 2) + r;
                const int col = n0 + wn + (j << 4) + m16;
                if (F32OUT)
                    ((float*)C)[(size_t)row * N + col] = acc[i][j][r];
                else
                    ((__hip_bfloat16*)C)[(size_t)row * N + col] =
                        __float2bfloat16(acc[i][j][r]);
            }
}

// Block-sparse flash attention. Grid (qblock=64, head=16, batch=2), 256 thr.
// ROUND-2 CHANGES (T14 + barrier cut + T5):
//  - async reg-stage: next tile's K/V global loads issue right after the
//    staging barrier, consumed at next iteration's LDS write (full tile of
//    QK+softmax+PV hides HBM latency; loads were previously serial between
//    barriers).
//  - removed 3rd __syncthreads: P scratch is PER-WAVE (wave w writes and
//    reads Pb[w]); wave-local s_waitcnt lgkmcnt(0) + sched_barrier suffices.
//  - s_setprio(1) around QK and PV MFMA clusters (T5; blocks on a CU are
//    independent, 3 blocks/CU co-resident).
//  - __launch_bounds__(256, 3): pin 3 blocks/CU (LDS = 45 KB allows 3; keep
//    VGPR <= 170 so the added kr/vr prefetch regs don't drop occupancy).
__global__ __launch_bounds__(256, 3) void attn_kernel(
    const __hip_bfloat16* __restrict__ qkv,
    __hip_bfloat16* __restrict__ outb)
{
    const int i   = blockIdx.x;   // q block
    const int h   = blockIdx.y;
    const int b   = blockIdx.z;
    const int kvh = h >> 2;
    const int tid  = threadIdx.x;
    const int lane = tid & 63;
    const int w    = tid >> 6;
    const int m16  = lane & 15;
    const int q8   = lane >> 4;

    __shared__ __align__(16) __hip_bfloat16 Ks[64 * 136];   // K rows padded +8
    __shared__ __align__(16) __hip_bfloat16 VT[128 * 72];   // V^T rows padded +8
    __shared__ __align__(16) __hip_bfloat16 Pb[4][16 * 72]; // per-wave P scratch

    // Q fragments (A-layout): row = lane&15 (+w*16), k-chunk = (lane>>4)*8
    bf16x8 qf[4];
    {
        const __hip_bfloat16* qp =
            qkv + (size_t)(b * Tlen + i * BLKQ + w * 16 + m16) * QKVC + h * Dh + q8 * 8;
        for (int ks = 0; ks < 4; ++ks) qf[ks] = *(const bf16x8*)(qp + ks * 32);
    }

    f32x4 o[8] = {};
    float mrow[4] = {-1e30f, -1e30f, -1e30f, -1e30f};
    float lrow[4] = {0.f, 0.f, 0.f, 0.f};

    const int nsel = (i + 1 < 9) ? (i + 1) : 9;
    auto kb_of = [&](int j) { return (i <= 7) ? j : ((j == 0) ? 0 : (i - 8 + j)); };

    // Prefetch tile 0 into registers.
    bf16x8 kr[4], vr[4];
    {
        const __hip_bfloat16* kbase =
            qkv + (size_t)(b * Tlen + kb_of(0) * BLKQ) * QKVC + HID + kvh * Dh;
        const __hip_bfloat16* vbase = kbase + 512;
        #pragma unroll
        for (int t = 0; t < 4; ++t) {
            const int c = tid + t * 256;
            kr[t] = *(const bf16x8*)(kbase + (size_t)(c >> 4) * QKVC + (c & 15) * 8);
            vr[t] = *(const bf16x8*)(vbase + (size_t)(c & 63) * QKVC + (c >> 6) * 8);
        }
    }

    for (int j = 0; j < nsel; ++j) {
        const int kb = kb_of(j);

        __syncthreads();  // prev iter's LDS reads (Ks/VT/Pb) complete
        // K: row-major vector writes (b128, conflict-free)
        #pragma unroll
        for (int t = 0; t < 4; ++t) {
            const int c = tid + t * 256;
            *(bf16x8*)&Ks[(c >> 4) * 136 + (c & 15) * 8] = kr[t];
        }
        // V^T: scalar transpose; key = lane => 32 banks 2-way (free per m136)
        #pragma unroll
        for (int t = 0; t < 4; ++t) {
            const int c = tid + t * 256;
            const int key = c & 63;
            const int d0  = (c >> 6) * 8;
            const __hip_bfloat16* ve = (const __hip_bfloat16*)&vr[t];
            #pragma unroll
            for (int jj = 0; jj < 8; ++jj)
                VT[(d0 + jj) * 72 + key] = ve[jj];
        }
        __syncthreads();  // staging visible

        // T14: issue next tile's loads now; consumed after next barrier.
        if (j + 1 < nsel) {
            const __hip_bfloat16* kbase =
                qkv + (size_t)(b * Tlen + kb_of(j + 1) * BLKQ) * QKVC + HID + kvh * Dh;
            const __hip_bfloat16* vbase = kbase + 512;
            #pragma unroll
            for (int t = 0; t < 4; ++t) {
                const int c = tid + t * 256;
                kr[t] = *(const bf16x8*)(kbase + (size_t)(c >> 4) * QKVC + (c & 15) * 8);
                vr[t] = *(const bf16x8*)(vbase + (size_t)(c & 63) * QKVC + (c >> 6) * 8);
            }
        }

        // S = Q K^T * scale  (16 q-rows x 64 keys per wave)
        float sv[4][4];
        __builtin_amdgcn_s_setprio(1);
        for (int nt = 0; nt < 4; ++nt) {
            f32x4 s = {0.f, 0.f, 0.f, 0.f};
            for (int ks = 0; ks < 4; ++ks) {
                bf16x8 kf = *(const bf16x8*)&Ks[(nt * 16 + m16) * 136 + ks * 32 + q8 * 8];
                s = MFMA16(qf[ks], kf, s);
            }
            for (int r = 0; r < 4; ++r) sv[nt][r] = s[r] * SCALE_C;
        }
        __builtin_amdgcn_s_setprio(0);
        if (kb == i) {  // causal mask on self block
            for (int nt = 0; nt < 4; ++nt) {
                const int key = nt * 16 + m16;
                for (int r = 0; r < 4; ++r) {
                    const int qr = w * 16 + q8 * 4 + r;
                    if (key > qr) sv[nt][r] = -1e9f;
                }
            }
        }

        // online softmax update (per row r; stats across 16 col-lanes)
        float alpha[4];
        for (int r = 0; r < 4; ++r) {
            float mx = fmaxf(fmaxf(sv[0][r], sv[1][r]), fmaxf(sv[2][r], sv[3][r]));
            for (int off = 1; off < 16; off <<= 1) mx = fmaxf(mx, __shfl_xor(mx, off, 64));
            const float newm = fmaxf(mrow[r], mx);
            alpha[r] = __expf(mrow[r] - newm);
            mrow[r] = newm;
            float rs = 0.f;
            for (int nt = 0; nt < 4; ++nt) {
                const float p = __expf(sv[nt][r] - newm);
                sv[nt][r] = p;
                rs += p;
            }
            for (int off = 1; off < 16; off <<= 1) rs += __shfl_xor(rs, off, 64);
            lrow[r] = lrow[r] * alpha[r] + rs;
        }

        // P: C-layout -> per-wave LDS -> A-layout (wave-local ordering only)
        __hip_bfloat16* Pw = &Pb[w][0];
        for (int nt = 0; nt < 4; ++nt)
            for (int r = 0; r < 4; ++r)
                Pw[(q8 * 4 + r) * 72 + nt * 16 + m16] = __float2bfloat16(sv[nt][r]);

        for (int dt = 0; dt < 8; ++dt)
            for (int r = 0; r < 4; ++r)
                o[dt][r] *= alpha[r];

        // P writes and reads are same-wave (Pb[w]): drain DS queue, pin order.
        asm volatile("s_waitcnt lgkmcnt(0)" ::: "memory");
        __builtin_amdgcn_sched_barrier(0);

        // O += P V  (k-dim = 64 keys, 2 k-steps; 8 d-tiles)
        __builtin_amdgcn_s_setprio(1);
        for (int kk = 0; kk < 2; ++kk) {
            bf16x8 pf = *(const bf16x8*)&Pw[m16 * 72 + kk * 32 + q8 * 8];
            for (int dt = 0; dt < 8; ++dt) {
                bf16x8 vf = *(const bf16x8*)&VT[(dt * 16 + m16) * 72 + kk * 32 + q8 * 8];
                o[dt] = MFMA16(pf, vf, o[dt]);
            }
        }
        __builtin_amdgcn_s_setprio(0);
    }

    // epilogue: O * (1/l) -> attn buffer [B*T][H*D] (bf16)
    float rcp[4];
    for (int r = 0; r < 4; ++r) rcp[r] = 1.0f / lrow[r];
    __hip_bfloat16* op = outb + (size_t)(b * Tlen + i * BLKQ) * (Hq * Dh) + h * Dh;
    for (int dt = 0; dt < 8; ++dt)
        for (int r = 0; r < 4; ++r) {
            const float val = o[dt][r] * rcp[r];
            op[(size_t)(w * 16 + q8 * 4 + r) * (Hq * Dh) + dt * 16 + m16] =
                __float2bfloat16(val);
        }
}

extern "C" void kernel_launch(void* const* d_in, const int* in_sizes, int n_in,
                              void* d_out, int out_size, void* d_ws, size_t ws_size,
                              hipStream_t stream) {
    const float* hs   = (const float*)d_in[0];
    const float* cosb = (const float*)d_in[1];
    const float* sinb = (const float*)d_in[2];
    const float* Wq   = (const float*)d_in[3];
    const float* Wk   = (const float*)d_in[4];
    const float* Wv   = (const float*)d_in[5];
    const float* Wo   = (const float*)d_in[6];

    const int M = Bsz * Tlen;                 // 8192
    const int nHS = M * HID;
    const int nWq = Hq * Dh * HID;
    const int nWk = HKV * Dh * HID;
    const int nWv = nWk;
    const int nWo = HID * Hq * Dh;

    __hip_bfloat16* hsb  = (__hip_bfloat16*)d_ws;
    __hip_bfloat16* wqb  = hsb + nHS;
    __hip_bfloat16* wkb  = wqb + nWq;
    __hip_bfloat16* wvb  = wkb + nWk;
    __hip_bfloat16* wob  = wvb + nWv;
    __hip_bfloat16* qkv  = wob + nWo;               // [8192][3072]
    __hip_bfloat16* attn = qkv + (size_t)M * QKVC;  // [8192][2048]

    // 0) f32 -> bf16 conversion of hs + all weights
    cvt_kernel<<<dim3(8192, 5), 256, 0, stream>>>(
        hs, Wq, Wk, Wv, Wo, hsb, nHS, nWq, nWk, nWv, nWo);
    // 1) fused QKV projection + RoPE epilogue (bf16 out), 256sq counted-vmcnt
    gemm256<true, false><<<dim3((QKVC / 256) * (M / 256)), 512, 0, stream>>>(
        hsb, wqb, wkb, wvb, HID, HID + 512, qkv, M, QKVC, HID, cosb, sinb);
    // 2) block-sparse attention (bf16, T14 reg-prefetch pipeline)
    attn_kernel<<<dim3(NBLK, Hq, Bsz), 256, 0, stream>>>(qkv, attn);
    // 3) output projection (f32 out to d_out), 256sq counted-vmcnt
    gemm256<false, true><<<dim3((HID / 256) * (M / 256)), 512, 0, stream>>>(
        attn, wob, wob, wob, HID, HID, d_out, M, HID, HID, nullptr, nullptr);
}

// Round 3
// 430.106 us; speedup vs baseline: 1.1458x; 1.0481x over previous
//
#include <hip/hip_runtime.h>
#include <hip/hip_bf16.h>

// Problem constants (HumanVAttention: B=2,T=4096,HID=2048,H=16,HKV=4,D=128,
// ROT=64, BLK=64, LOCAL=8, GLOB=1).
// DTYPE (established empirically): harness presents ALL tensors in f32.
// Internal compute bf16 MFMA; I/O f32. Threshold is bf16-grade.
#define Hq   16
#define HKV  4
#define Dh   128
#define ROT  64
#define BLKQ 64
#define NBLK 64      // T/BLK
#define Tlen 4096
#define Bsz  2
#define HID  2048
#define QKVC 3072    // 2048 q + 512 k + 512 v
#define SCALE_C 0.08838834764831845f

typedef __attribute__((ext_vector_type(8))) short bf16x8;
typedef __attribute__((ext_vector_type(4))) float f32x4;

#define MFMA16(a, b, c) __builtin_amdgcn_mfma_f32_16x16x32_bf16((a), (b), (c), 0, 0, 0)

__device__ __forceinline__ void async_copy16(__hip_bfloat16* lds, const __hip_bfloat16* g) {
    __builtin_amdgcn_global_load_lds(
        (const __attribute__((address_space(1))) void*)g,
        (__attribute__((address_space(3))) void*)lds,
        16, 0, 0);
}

// f32 -> bf16 bulk convert. blockIdx.y selects tensor {hs, Wq, Wk, Wv, Wo}.
__global__ __launch_bounds__(256) void cvt_kernel(
    const float* __restrict__ s0, const float* __restrict__ s1,
    const float* __restrict__ s2, const float* __restrict__ s3,
    const float* __restrict__ s4,
    __hip_bfloat16* __restrict__ base,
    int n0, int n1, int n2, int n3, int n4)
{
    const float* src;
    size_t off, n;
    switch (blockIdx.y) {
        case 0:  src = s0; off = 0;                          n = n0; break;
        case 1:  src = s1; off = (size_t)n0;                 n = n1; break;
        case 2:  src = s2; off = (size_t)n0 + n1;            n = n2; break;
        case 3:  src = s3; off = (size_t)n0 + n1 + n2;       n = n3; break;
        default: src = s4; off = (size_t)n0 + n1 + n2 + n3;  n = n4; break;
    }
    __hip_bfloat16* dst = base + off;
    const size_t stride = (size_t)gridDim.x * 2048;
    for (size_t i = ((size_t)blockIdx.x * 256 + threadIdx.x) * 8; i < n; i += stride) {
        const float4 a = *(const float4*)(src + i);
        const float4 b = *(const float4*)(src + i + 4);
        union { bf16x8 v; __hip_bfloat16 e[8]; } u;
        u.e[0] = __float2bfloat16(a.x); u.e[1] = __float2bfloat16(a.y);
        u.e[2] = __float2bfloat16(a.z); u.e[3] = __float2bfloat16(a.w);
        u.e[4] = __float2bfloat16(b.x); u.e[5] = __float2bfloat16(b.y);
        u.e[6] = __float2bfloat16(b.z); u.e[7] = __float2bfloat16(b.w);
        *(bf16x8*)(dst + i) = u.v;
    }
}

// C[M,N] = A[M,K] * B[N,K]^T, bf16 in. 128x128 tile, BK=64, 4 waves, 256 thr,
// DOUBLE-BUFFERED 64 KiB LDS => 2 independent blocks/CU (the round-3 theory:
// cross-block overlap feeds the LDS and MFMA pipes concurrently; the 256sq
// 1-block/CU lockstep serialized them at 28% MfmaUtil).
// One barrier per K-tile: within tile u all frag reads hit buf[P] and all
// stages target buf[P^1], so the only sync needed is vmcnt(0)+s_barrier at
// the tile boundary (stage->read handoff + read->overwrite handoff both
// follow from per-wave lgkm0 drains before the barrier).
// Swizzle (proven in R0 gemm_bt): LDS slot (row,cs) holds global chunk
// cg = cs ^ (row&7); staging pre-swizzles the source, reads XOR the chunk.
template <bool ROPE_, bool F32OUT>
__global__ __launch_bounds__(256, 2) void gemm128db(
    const __hip_bfloat16* __restrict__ A,
    const __hip_bfloat16* __restrict__ B0,
    const __hip_bfloat16* __restrict__ B1,
    const __hip_bfloat16* __restrict__ B2,
    int n1c, int n2c,
    void* __restrict__ C,
    int M, int N, int K,
    const float* __restrict__ cosb,
    const float* __restrict__ sinb)
{
    __shared__ __align__(16) __hip_bfloat16 As[2][128 * 64];
    __shared__ __align__(16) __hip_bfloat16 Bs[2][128 * 64];

    const int m0 = blockIdx.y * 128;
    const int n0 = blockIdx.x * 128;
    const __hip_bfloat16* Bp;
    int nb;
    if (n0 < n1c)      { Bp = B0; nb = n0; }
    else if (n0 < n2c) { Bp = B1; nb = n0 - n1c; }
    else               { Bp = B2; nb = n0 - n2c; }

    const int tid  = threadIdx.x;
    const int lane = tid & 63;
    const int w    = tid >> 6;          // wave 0..3
    const int wm   = (w >> 1) * 64;
    const int wn   = (w & 1) * 64;
    const int lr   = lane >> 3;         // row within 8-row staging group
    const int lc   = lane & 7;          // chunk slot
    const int m16  = lane & 15;
    const int q8   = lane >> 4;
    const int NT   = K >> 6;

    f32x4 acc[4][4] = {};

    auto stageA = [&](int buf, int kc) {
        #pragma unroll
        for (int ii = 0; ii < 4; ++ii) {
            const int r8 = w * 32 + ii * 8;
            const int r  = r8 + lr;
            const int cg = lc ^ (r & 7);
            async_copy16(&As[buf][r8 * 64], A + (size_t)(m0 + r) * K + kc + cg * 8);
        }
    };
    auto stageB = [&](int buf, int kc) {
        #pragma unroll
        for (int ii = 0; ii < 4; ++ii) {
            const int r8 = w * 32 + ii * 8;
            const int r  = r8 + lr;
            const int cg = lc ^ (r & 7);
            async_copy16(&Bs[buf][r8 * 64], Bp + (size_t)(nb + r) * K + kc + cg * 8);
        }
    };

    // Prologue: tile 0 -> buf0, full drain.
    stageA(0, 0);
    stageB(0, 0);
    asm volatile("s_waitcnt vmcnt(0)" ::: "memory");
    __builtin_amdgcn_s_barrier();

    for (int u = 0; u < NT; ++u) {
        const int P  = u & 1;
        // u+1 == NT: re-stage tile 0 into buf[P^1] (never read; keeps all
        // global addresses in-bounds).
        const int kN = (u + 1 < NT ? u + 1 : 0) << 6;
        const __hip_bfloat16* Ap_ = As[P];
        const __hip_bfloat16* Bq_ = Bs[P];

        bf16x8 a0[4], b0[4], a1[4], b1[4];

        // ---- phase 1: k0 frags; stage A(u+1); MFMA k0
        #pragma unroll
        for (int t = 0; t < 4; ++t) {
            const int row = wm + t * 16 + m16;
            const int csA = q8 ^ (row & 7);
            a0[t] = *(const bf16x8*)&Ap_[row * 64 + csA * 8];
            const int col = wn + t * 16 + m16;
            const int csB = q8 ^ (col & 7);
            b0[t] = *(const bf16x8*)&Bq_[col * 64 + csB * 8];
        }
        stageA(P ^ 1, kN);
        asm volatile("s_waitcnt lgkmcnt(0)" ::: "memory");
        __builtin_amdgcn_s_setprio(1);
        #pragma unroll
        for (int i = 0; i < 4; ++i)
            #pragma unroll
            for (int j = 0; j < 4; ++j)
                acc[i][j] = MFMA16(a0[i], b0[j], acc[i][j]);
        __builtin_amdgcn_s_setprio(0);

        // ---- phase 2: k1 frags; stage B(u+1); MFMA k1
        #pragma unroll
        for (int t = 0; t < 4; ++t) {
            const int row = wm + t * 16 + m16;
            const int csA = (4 + q8) ^ (row & 7);
            a1[t] = *(const bf16x8*)&Ap_[row * 64 + csA * 8];
            const int col = wn + t * 16 + m16;
            const int csB = (4 + q8) ^ (col & 7);
            b1[t] = *(const bf16x8*)&Bq_[col * 64 + csB * 8];
        }
        stageB(P ^ 1, kN);
        asm volatile("s_waitcnt lgkmcnt(0)" ::: "memory");
        __builtin_amdgcn_s_setprio(1);
        #pragma unroll
        for (int i = 0; i < 4; ++i)
            #pragma unroll
            for (int j = 0; j < 4; ++j)
                acc[i][j] = MFMA16(a1[i], b1[j], acc[i][j]);
        __builtin_amdgcn_s_setprio(0);

        // tile boundary: next-tile stages complete + all waves past reads
        asm volatile("s_waitcnt vmcnt(0)" ::: "memory");
        __builtin_amdgcn_s_barrier();
    }

    // Fused RoPE: q/k head tiles (n0 < n2c == 2560), rot half (wn == 0).
    // cols = j*16 + m16; pair (d, d+32) = regs (j, j+2), j in {0,1};
    // cos[d]==cos[d+32] (emb = concat(freqs,freqs)). cos/sin are f32.
    if (ROPE_ && n0 < n2c && wn == 0) {
        #pragma unroll
        for (int i = 0; i < 4; ++i)
            #pragma unroll
            for (int r = 0; r < 4; ++r) {
                const int bt = m0 + wm + i * 16 + q8 * 4 + r;   // b*T + t
                #pragma unroll
                for (int j = 0; j < 2; ++j) {
                    const int d = j * 16 + m16;
                    const float c = cosb[(size_t)bt * ROT + d];
                    const float s = sinb[(size_t)bt * ROT + d];
                    const float x1 = acc[i][j][r];
                    const float x2 = acc[i][j + 2][r];
                    acc[i][j][r]     = x1 * c - x2 * s;
                    acc[i][j + 2][r] = x2 * c + x1 * s;
                }
            }
    }

    // epilogue: C layout col=lane&15, row=(lane>>4)*4+reg
    #pragma unroll
    for (int i = 0; i < 4; ++i)
        #pragma unroll
        for (int j = 0; j < 4; ++j)
            #pragma unroll
            for (int r = 0; r < 4; ++r) {
                const int row = m0 + wm + i * 16 + q8 * 4 + r;
                const int col = n0 + wn + j * 16 + m16;
                if (F32OUT)
                    ((float*)C)[(size_t)row * N + col] = acc[i][j][r];
                else
                    ((__hip_bfloat16*)C)[(size_t)row * N + col] =
                        __float2bfloat16(acc[i][j][r]);
            }
}

// V pre-transpose: qkv V block [b][t][kvh][d] -> VTg[(b*4+kvh)*128 + d][t]
// (d-major, bf16). 8 MB tensor, done ONCE so attn can stage V^T with vector
// writes instead of re-doing a 32-scalar-ds_write transpose per consumer
// (each V block is read by ~8.4 q-blocks). Scalar strided global reads are
// L1-resident (64-row x 256 B working set per block); writes coalesced.
__global__ __launch_bounds__(256) void vtrans_kernel(
    const __hip_bfloat16* __restrict__ qkv,
    __hip_bfloat16* __restrict__ vtg)
{
    const int tb = blockIdx.x;   // t block of 64 (0..63)
    const int pr = blockIdx.y;   // b*4 + kvh (0..7)
    const __hip_bfloat16* src =
        qkv + ((size_t)(pr >> 2) * Tlen + tb * 64) * QKVC + HID + 512 + (pr & 3) * Dh;
    __hip_bfloat16* dst = vtg + (size_t)pr * Dh * Tlen + tb * 64;
    const int tid = threadIdx.x;
    #pragma unroll
    for (int t2 = 0; t2 < 4; ++t2) {
        const int c  = tid + t2 * 256;   // 0..1023: d = c>>3, t0 = (c&7)*8
        const int d  = c >> 3;
        const int t0 = (c & 7) * 8;
        union { bf16x8 v; __hip_bfloat16 e[8]; } u;
        #pragma unroll
        for (int j = 0; j < 8; ++j)
            u.e[j] = src[(size_t)(t0 + j) * QKVC + d];
        *(bf16x8*)(dst + (size_t)d * Tlen + t0) = u.v;
    }
}

// Block-sparse flash attention. Grid (qblock=64, head=16, batch=2), 256 thr.
// ROUND-3 CHANGE: V^T staged from pre-transposed VTg with 4 vector b128
// LDS writes per thread (was: 32 scalar ds_write_b16 transpose per thread
// per kv-block — instruction-count hot spot comparable to the MFMA time).
// PV fragment reads and all math unchanged. T14 reg-prefetch, per-wave P
// scratch (no 3rd barrier), setprio retained from round 2.
__global__ __launch_bounds__(256, 3) void attn_kernel(
    const __hip_bfloat16* __restrict__ qkv,
    const __hip_bfloat16* __restrict__ vtg,
    __hip_bfloat16* __restrict__ outb)
{
    const int i   = blockIdx.x;   // q block
    const int h   = blockIdx.y;
    const int b   = blockIdx.z;
    const int kvh = h >> 2;
    const int tid  = threadIdx.x;
    const int lane = tid & 63;
    const int w    = tid >> 6;
    const int m16  = lane & 15;
    const int q8   = lane >> 4;

    __shared__ __align__(16) __hip_bfloat16 Ks[64 * 136];   // K rows padded +8
    __shared__ __align__(16) __hip_bfloat16 VT[128 * 72];   // V^T rows padded +8
    __shared__ __align__(16) __hip_bfloat16 Pb[4][16 * 72]; // per-wave P scratch

    // Q fragments (A-layout): row = lane&15 (+w*16), k-chunk = (lane>>4)*8
    bf16x8 qf[4];
    {
        const __hip_bfloat16* qp =
            qkv + (size_t)(b * Tlen + i * BLKQ + w * 16 + m16) * QKVC + h * Dh + q8 * 8;
        for (int ks = 0; ks < 4; ++ks) qf[ks] = *(const bf16x8*)(qp + ks * 32);
    }

    f32x4 o[8] = {};
    float mrow[4] = {-1e30f, -1e30f, -1e30f, -1e30f};
    float lrow[4] = {0.f, 0.f, 0.f, 0.f};

    const int nsel = (i + 1 < 9) ? (i + 1) : 9;
    auto kb_of = [&](int j) { return (i <= 7) ? j : ((j == 0) ? 0 : (i - 8 + j)); };

    const __hip_bfloat16* vtbase = vtg + (size_t)(b * HKV + kvh) * Dh * Tlen;

    // Prefetch tile 0 into registers.
    bf16x8 kr[4], vr[4];
    {
        const int kb0 = kb_of(0);
        const __hip_bfloat16* kbase =
            qkv + (size_t)(b * Tlen + kb0 * BLKQ) * QKVC + HID + kvh * Dh;
        #pragma unroll
        for (int t = 0; t < 4; ++t) {
            const int c = tid + t * 256;
            kr[t] = *(const bf16x8*)(kbase + (size_t)(c >> 4) * QKVC + (c & 15) * 8);
            vr[t] = *(const bf16x8*)(vtbase + (size_t)(c >> 3) * Tlen
                                     + kb0 * BLKQ + (c & 7) * 8);
        }
    }

    for (int j = 0; j < nsel; ++j) {
        const int kb = kb_of(j);

        __syncthreads();  // prev iter's LDS reads (Ks/VT/Pb) complete
        // K: row-major vector writes (b128, conflict-free)
        #pragma unroll
        for (int t = 0; t < 4; ++t) {
            const int c = tid + t * 256;
            *(bf16x8*)&Ks[(c >> 4) * 136 + (c & 15) * 8] = kr[t];
        }
        // V^T: vector writes from VTg rows (b128; 144 B row stride, aligned)
        #pragma unroll
        for (int t = 0; t < 4; ++t) {
            const int c = tid + t * 256;
            *(bf16x8*)&VT[(c >> 3) * 72 + (c & 7) * 8] = vr[t];
        }
        __syncthreads();  // staging visible

        // T14: issue next tile's loads now; consumed after next barrier.
        if (j + 1 < nsel) {
            const int kbn = kb_of(j + 1);
            const __hip_bfloat16* kbase =
                qkv + (size_t)(b * Tlen + kbn * BLKQ) * QKVC + HID + kvh * Dh;
            #pragma unroll
            for (int t = 0; t < 4; ++t) {
                const int c = tid + t * 256;
                kr[t] = *(const bf16x8*)(kbase + (size_t)(c >> 4) * QKVC + (c & 15) * 8);
                vr[t] = *(const bf16x8*)(vtbase + (size_t)(c >> 3) * Tlen
                                         + kbn * BLKQ + (c & 7) * 8);
            }
        }

        // S = Q K^T * scale  (16 q-rows x 64 keys per wave)
        float sv[4][4];
        __builtin_amdgcn_s_setprio(1);
        for (int nt = 0; nt < 4; ++nt) {
            f32x4 s = {0.f, 0.f, 0.f, 0.f};
            for (int ks = 0; ks < 4; ++ks) {
                bf16x8 kf = *(const bf16x8*)&Ks[(nt * 16 + m16) * 136 + ks * 32 + q8 * 8];
                s = MFMA16(qf[ks], kf, s);
            }
            for (int r = 0; r < 4; ++r) sv[nt][r] = s[r] * SCALE_C;
        }
        __builtin_amdgcn_s_setprio(0);
        if (kb == i) {  // causal mask on self block
            for (int nt = 0; nt < 4; ++nt) {
                const int key = nt * 16 + m16;
                for (int r = 0; r < 4; ++r) {
                    const int qr = w * 16 + q8 * 4 + r;
                    if (key > qr) sv[nt][r] = -1e9f;
                }
            }
        }

        // online softmax update (per row r; stats across 16 col-lanes)
        float alpha[4];
        for (int r = 0; r < 4; ++r) {
            float mx = fmaxf(fmaxf(sv[0][r], sv[1][r]), fmaxf(sv[2][r], sv[3][r]));
            for (int off = 1; off < 16; off <<= 1) mx = fmaxf(mx, __shfl_xor(mx, off, 64));
            const float newm = fmaxf(mrow[r], mx);
            alpha[r] = __expf(mrow[r] - newm);
            mrow[r] = newm;
            float rs = 0.f;
            for (int nt = 0; nt < 4; ++nt) {
                const float p = __expf(sv[nt][r] - newm);
                sv[nt][r] = p;
                rs += p;
            }
            for (int off = 1; off < 16; off <<= 1) rs += __shfl_xor(rs, off, 64);
            lrow[r] = lrow[r] * alpha[r] + rs;
        }

        // P: C-layout -> per-wave LDS -> A-layout (wave-local ordering only)
        __hip_bfloat16* Pw = &Pb[w][0];
        for (int nt = 0; nt < 4; ++nt)
            for (int r = 0; r < 4; ++r)
                Pw[(q8 * 4 + r) * 72 + nt * 16 + m16] = __float2bfloat16(sv[nt][r]);

        for (int dt = 0; dt < 8; ++dt)
            for (int r = 0; r < 4; ++r)
                o[dt][r] *= alpha[r];

        // P writes and reads are same-wave (Pb[w]): drain DS queue, pin order.
        asm volatile("s_waitcnt lgkmcnt(0)" ::: "memory");
        __builtin_amdgcn_sched_barrier(0);

        // O += P V  (k-dim = 64 keys, 2 k-steps; 8 d-tiles)
        __builtin_amdgcn_s_setprio(1);
        for (int kk = 0; kk < 2; ++kk) {
            bf16x8 pf = *(const bf16x8*)&Pw[m16 * 72 + kk * 32 + q8 * 8];
            for (int dt = 0; dt < 8; ++dt) {
                bf16x8 vf = *(const bf16x8*)&VT[(dt * 16 + m16) * 72 + kk * 32 + q8 * 8];
                o[dt] = MFMA16(pf, vf, o[dt]);
            }
        }
        __builtin_amdgcn_s_setprio(0);
    }

    // epilogue: O * (1/l) -> attn buffer [B*T][H*D] (bf16)
    float rcp[4];
    for (int r = 0; r < 4; ++r) rcp[r] = 1.0f / lrow[r];
    __hip_bfloat16* op = outb + (size_t)(b * Tlen + i * BLKQ) * (Hq * Dh) + h * Dh;
    for (int dt = 0; dt < 8; ++dt)
        for (int r = 0; r < 4; ++r) {
            const float val = o[dt][r] * rcp[r];
            op[(size_t)(w * 16 + q8 * 4 + r) * (Hq * Dh) + dt * 16 + m16] =
                __float2bfloat16(val);
        }
}

extern "C" void kernel_launch(void* const* d_in, const int* in_sizes, int n_in,
                              void* d_out, int out_size, void* d_ws, size_t ws_size,
                              hipStream_t stream) {
    const float* hs   = (const float*)d_in[0];
    const float* cosb = (const float*)d_in[1];
    const float* sinb = (const float*)d_in[2];
    const float* Wq   = (const float*)d_in[3];
    const float* Wk   = (const float*)d_in[4];
    const float* Wv   = (const float*)d_in[5];
    const float* Wo   = (const float*)d_in[6];

    const int M = Bsz * Tlen;                 // 8192
    const int nHS = M * HID;
    const int nWq = Hq * Dh * HID;
    const int nWk = HKV * Dh * HID;
    const int nWv = nWk;
    const int nWo = HID * Hq * Dh;

    // ws layout (bf16): hs | Wq | Wk | Wv | Wo | qkv | attn | vtg
    __hip_bfloat16* hsb  = (__hip_bfloat16*)d_ws;
    __hip_bfloat16* wqb  = hsb + nHS;
    __hip_bfloat16* wkb  = wqb + nWq;
    __hip_bfloat16* wvb  = wkb + nWk;
    __hip_bfloat16* wob  = wvb + nWv;
    __hip_bfloat16* qkv  = wob + nWo;               // [8192][3072]
    __hip_bfloat16* attn = qkv + (size_t)M * QKVC;  // [8192][2048]
    __hip_bfloat16* vtg  = attn + (size_t)M * (Hq * Dh);  // [8][128][4096]

    // 0) f32 -> bf16 conversion of hs + all weights
    cvt_kernel<<<dim3(8192, 5), 256, 0, stream>>>(
        hs, Wq, Wk, Wv, Wo, hsb, nHS, nWq, nWk, nWv, nWo);
    // 1) fused QKV projection + RoPE epilogue (bf16 out), 128sq dbuf
    gemm128db<true, false><<<dim3(QKVC / 128, M / 128), 256, 0, stream>>>(
        hsb, wqb, wkb, wvb, HID, HID + 512, qkv, M, QKVC, HID, cosb, sinb);
    // 2) V pre-transpose for attention
    vtrans_kernel<<<dim3(NBLK, Bsz * HKV), 256, 0, stream>>>(qkv, vtg);
    // 3) block-sparse attention (bf16)
    attn_kernel<<<dim3(NBLK, Hq, Bsz), 256, 0, stream>>>(qkv, vtg, attn);
    // 4) output projection (f32 out to d_out), 128sq dbuf
    gemm128db<false, true><<<dim3(HID / 128, M / 128), 256, 0, stream>>>(
        attn, wob, wob, wob, HID, HID, d_out, M, HID, HID, nullptr, nullptr);
}

// Round 4
// 415.755 us; speedup vs baseline: 1.1853x; 1.0345x over previous
//
#include <hip/hip_runtime.h>
#include <hip/hip_bf16.h>

// Problem constants (HumanVAttention: B=2,T=4096,HID=2048,H=16,HKV=4,D=128,
// ROT=64, BLK=64, LOCAL=8, GLOB=1).
// DTYPE (established empirically): harness presents ALL tensors in f32.
// Internal compute bf16 MFMA; I/O f32. Threshold is bf16-grade.
#define Hq   16
#define HKV  4
#define Dh   128
#define ROT  64
#define BLKQ 64
#define NBLK 64      // T/BLK
#define Tlen 4096
#define Bsz  2
#define HID  2048
#define QKVC 3072    // 2048 q + 512 k + 512 v
#define SCALE_C 0.08838834764831845f

typedef __attribute__((ext_vector_type(8))) short bf16x8;
typedef __attribute__((ext_vector_type(4))) float f32x4;

#define MFMA16(a, b, c) __builtin_amdgcn_mfma_f32_16x16x32_bf16((a), (b), (c), 0, 0, 0)

__device__ __forceinline__ void async_copy16(__hip_bfloat16* lds, const __hip_bfloat16* g) {
    __builtin_amdgcn_global_load_lds(
        (const __attribute__((address_space(1))) void*)g,
        (__attribute__((address_space(3))) void*)lds,
        16, 0, 0);
}

// f32 -> bf16 bulk convert. blockIdx.y selects tensor {hs, Wq, Wk, Wv, Wo}.
__global__ __launch_bounds__(256) void cvt_kernel(
    const float* __restrict__ s0, const float* __restrict__ s1,
    const float* __restrict__ s2, const float* __restrict__ s3,
    const float* __restrict__ s4,
    __hip_bfloat16* __restrict__ base,
    int n0, int n1, int n2, int n3, int n4)
{
    const float* src;
    size_t off, n;
    switch (blockIdx.y) {
        case 0:  src = s0; off = 0;                          n = n0; break;
        case 1:  src = s1; off = (size_t)n0;                 n = n1; break;
        case 2:  src = s2; off = (size_t)n0 + n1;            n = n2; break;
        case 3:  src = s3; off = (size_t)n0 + n1 + n2;       n = n3; break;
        default: src = s4; off = (size_t)n0 + n1 + n2 + n3;  n = n4; break;
    }
    __hip_bfloat16* dst = base + off;
    const size_t stride = (size_t)gridDim.x * 2048;
    for (size_t i = ((size_t)blockIdx.x * 256 + threadIdx.x) * 8; i < n; i += stride) {
        const float4 a = *(const float4*)(src + i);
        const float4 b = *(const float4*)(src + i + 4);
        union { bf16x8 v; __hip_bfloat16 e[8]; } u;
        u.e[0] = __float2bfloat16(a.x); u.e[1] = __float2bfloat16(a.y);
        u.e[2] = __float2bfloat16(a.z); u.e[3] = __float2bfloat16(a.w);
        u.e[4] = __float2bfloat16(b.x); u.e[5] = __float2bfloat16(b.y);
        u.e[6] = __float2bfloat16(b.z); u.e[7] = __float2bfloat16(b.w);
        *(bf16x8*)(dst + i) = u.v;
    }
}

// C[M,N] = A[M,K] * B[N,K]^T, bf16 in. 128x128 tile, BK=64, 4 waves, 256 thr,
// double-buffered 64 KiB LDS => 2 independent blocks/CU (cross-block overlap
// feeds LDS and MFMA pipes concurrently; round-3 measured: 37% MfmaUtil,
// 3357 cy/K-tile/CU vs 1242 MFMA + ~2050 LDS busy).
//
// ROUND-4 CHANGE — eager-stage ("triple-buffer in time with 2 buffers"):
// r3 staged tile u+1 into buf[P^1] DURING tile u and drained vmcnt(0) at the
// tile boundary => the phase-2 stage (issued ~600 cy before the drain) exposed
// most of a raw HBM latency (~900 cy) EVERY tile = the ~1300 cy/tile bubble.
// Now tile u stages tile u+2 into buf[P] (the buffer tile u just READ), legal
// because bar1 certifies every wave's 16 frag reads are in registers
// (per-wave lgkmcnt(0) + s_barrier; sched_barrier(0) pins issue order per
// guide rule #18). Stage-to-consume gap = one full tile (>2000 cy) and the
// main loop never drains vmcnt to 0: vmcnt(8) at the boundary waits on loads
// issued TWO tiles ago (free), leaving this tile's 8 stage loads in flight.
// In-flight/thread at vmcnt(8): {tile u+1: 8 old, tile u+2: 8 new} -> waits
// exactly until u+1 complete; bar2 publishes it block-wide.
// Swizzle (proven): LDS slot (row,cs) holds global chunk cg = cs ^ (row&7).
template <bool ROPE_, bool F32OUT>
__global__ __launch_bounds__(256, 2) void gemm128db(
    const __hip_bfloat16* __restrict__ A,
    const __hip_bfloat16* __restrict__ B0,
    const __hip_bfloat16* __restrict__ B1,
    const __hip_bfloat16* __restrict__ B2,
    int n1c, int n2c,
    void* __restrict__ C,
    int M, int N, int K,
    const float* __restrict__ cosb,
    const float* __restrict__ sinb)
{
    __shared__ __align__(16) __hip_bfloat16 As[2][128 * 64];
    __shared__ __align__(16) __hip_bfloat16 Bs[2][128 * 64];

    const int m0 = blockIdx.y * 128;
    const int n0 = blockIdx.x * 128;
    const __hip_bfloat16* Bp;
    int nb;
    if (n0 < n1c)      { Bp = B0; nb = n0; }
    else if (n0 < n2c) { Bp = B1; nb = n0 - n1c; }
    else               { Bp = B2; nb = n0 - n2c; }

    const int tid  = threadIdx.x;
    const int lane = tid & 63;
    const int w    = tid >> 6;          // wave 0..3
    const int wm   = (w >> 1) * 64;
    const int wn   = (w & 1) * 64;
    const int lr   = lane >> 3;         // row within 8-row staging group
    const int lc   = lane & 7;          // chunk slot
    const int m16  = lane & 15;
    const int q8   = lane >> 4;
    const int NT   = K >> 6;            // 32 here (>= 3 assumed)

    f32x4 acc[4][4] = {};

    auto stageA = [&](int buf, int kc) {
        #pragma unroll
        for (int ii = 0; ii < 4; ++ii) {
            const int r8 = w * 32 + ii * 8;
            const int r  = r8 + lr;
            const int cg = lc ^ (r & 7);
            async_copy16(&As[buf][r8 * 64], A + (size_t)(m0 + r) * K + kc + cg * 8);
        }
    };
    auto stageB = [&](int buf, int kc) {
        #pragma unroll
        for (int ii = 0; ii < 4; ++ii) {
            const int r8 = w * 32 + ii * 8;
            const int r  = r8 + lr;
            const int cg = lc ^ (r & 7);
            async_copy16(&Bs[buf][r8 * 64], Bp + (size_t)(nb + r) * K + kc + cg * 8);
        }
    };

    // Prologue: tile0 -> buf0 (8 loads/thread), tile1 -> buf1 (8 loads).
    // vmcnt(8) = tile0 complete, tile1 may still fly.
    stageA(0, 0);
    stageB(0, 0);
    stageA(1, 64);
    stageB(1, 64);
    asm volatile("s_waitcnt vmcnt(8)" ::: "memory");
    __builtin_amdgcn_s_barrier();

    for (int u = 0; u < NT; ++u) {
        const int P  = u & 1;
        const __hip_bfloat16* Ap_ = As[P];
        const __hip_bfloat16* Bq_ = Bs[P];

        // All 16 fragment reads of tile u (k0: cs=q8, k1: cs=4+q8).
        bf16x8 a0[4], b0[4], a1[4], b1[4];
        #pragma unroll
        for (int t = 0; t < 4; ++t) {
            const int row = wm + t * 16 + m16;
            const int col = wn + t * 16 + m16;
            a0[t] = *(const bf16x8*)&Ap_[row * 64 + ((q8)     ^ (row & 7)) * 8];
            b0[t] = *(const bf16x8*)&Bq_[col * 64 + ((q8)     ^ (col & 7)) * 8];
            a1[t] = *(const bf16x8*)&Ap_[row * 64 + ((4 + q8) ^ (row & 7)) * 8];
            b1[t] = *(const bf16x8*)&Bq_[col * 64 + ((4 + q8) ^ (col & 7)) * 8];
        }
        // Per-wave drain: all reads of buf[P] now in registers.
        asm volatile("s_waitcnt lgkmcnt(0)" ::: "memory");
        __builtin_amdgcn_sched_barrier(0);
        __builtin_amdgcn_s_barrier();            // bar1: whole block done reading buf[P]
        __builtin_amdgcn_sched_barrier(0);       // keep stages below bar1

        if (u + 2 < NT) {                        // eager-stage tile u+2 -> buf[P]
            stageA(P, (u + 2) << 6);
            stageB(P, (u + 2) << 6);
        }

        __builtin_amdgcn_s_setprio(1);
        #pragma unroll
        for (int i = 0; i < 4; ++i)
            #pragma unroll
            for (int j = 0; j < 4; ++j)
                acc[i][j] = MFMA16(a0[i], b0[j], acc[i][j]);
        #pragma unroll
        for (int i = 0; i < 4; ++i)
            #pragma unroll
            for (int j = 0; j < 4; ++j)
                acc[i][j] = MFMA16(a1[i], b1[j], acc[i][j]);
        __builtin_amdgcn_s_setprio(0);

        // Tile boundary: need tile u+1 (issued two tiles ago) complete.
        if (u + 2 < NT) {
            asm volatile("s_waitcnt vmcnt(8)" ::: "memory");
        } else {
            asm volatile("s_waitcnt vmcnt(0)" ::: "memory");
        }
        __builtin_amdgcn_s_barrier();            // bar2: buf[P^1] ready for tile u+1
    }

    // Fused RoPE: q/k head tiles (n0 < n2c == 2560), rot half (wn == 0).
    // cols = j*16 + m16; pair (d, d+32) = regs (j, j+2), j in {0,1};
    // cos[d]==cos[d+32] (emb = concat(freqs,freqs)). cos/sin are f32.
    if (ROPE_ && n0 < n2c && wn == 0) {
        #pragma unroll
        for (int i = 0; i < 4; ++i)
            #pragma unroll
            for (int r = 0; r < 4; ++r) {
                const int bt = m0 + wm + i * 16 + q8 * 4 + r;   // b*T + t
                #pragma unroll
                for (int j = 0; j < 2; ++j) {
                    const int d = j * 16 + m16;
                    const float c = cosb[(size_t)bt * ROT + d];
                    const float s = sinb[(size_t)bt * ROT + d];
                    const float x1 = acc[i][j][r];
                    const float x2 = acc[i][j + 2][r];
                    acc[i][j][r]     = x1 * c - x2 * s;
                    acc[i][j + 2][r] = x2 * c + x1 * s;
                }
            }
    }

    // epilogue: C layout col=lane&15, row=(lane>>4)*4+reg
    #pragma unroll
    for (int i = 0; i < 4; ++i)
        #pragma unroll
        for (int j = 0; j < 4; ++j)
            #pragma unroll
            for (int r = 0; r < 4; ++r) {
                const int row = m0 + wm + i * 16 + q8 * 4 + r;
                const int col = n0 + wn + j * 16 + m16;
                if (F32OUT)
                    ((float*)C)[(size_t)row * N + col] = acc[i][j][r];
                else
                    ((__hip_bfloat16*)C)[(size_t)row * N + col] =
                        __float2bfloat16(acc[i][j][r]);
            }
}

// V pre-transpose: qkv V block [b][t][kvh][d] -> VTg[(b*4+kvh)*128 + d][t]
// (d-major, bf16). 8 MB tensor, done ONCE so attn can stage V^T with vector
// writes instead of re-doing a 32-scalar-ds_write transpose per consumer
// (each V block is read by ~8.4 q-blocks). Scalar strided global reads are
// L1-resident (64-row x 256 B working set per block); writes coalesced.
__global__ __launch_bounds__(256) void vtrans_kernel(
    const __hip_bfloat16* __restrict__ qkv,
    __hip_bfloat16* __restrict__ vtg)
{
    const int tb = blockIdx.x;   // t block of 64 (0..63)
    const int pr = blockIdx.y;   // b*4 + kvh (0..7)
    const __hip_bfloat16* src =
        qkv + ((size_t)(pr >> 2) * Tlen + tb * 64) * QKVC + HID + 512 + (pr & 3) * Dh;
    __hip_bfloat16* dst = vtg + (size_t)pr * Dh * Tlen + tb * 64;
    const int tid = threadIdx.x;
    #pragma unroll
    for (int t2 = 0; t2 < 4; ++t2) {
        const int c  = tid + t2 * 256;   // 0..1023: d = c>>3, t0 = (c&7)*8
        const int d  = c >> 3;
        const int t0 = (c & 7) * 8;
        union { bf16x8 v; __hip_bfloat16 e[8]; } u;
        #pragma unroll
        for (int j = 0; j < 8; ++j)
            u.e[j] = src[(size_t)(t0 + j) * QKVC + d];
        *(bf16x8*)(dst + (size_t)d * Tlen + t0) = u.v;
    }
}

// Block-sparse flash attention. Grid (qblock=64, head=16, batch=2), 256 thr.
// V^T staged from pre-transposed VTg with vector b128 LDS writes; T14
// reg-prefetch of next tile's K/V; per-wave P scratch (no 3rd barrier);
// setprio around MFMA clusters. Unchanged from round 3.
__global__ __launch_bounds__(256, 3) void attn_kernel(
    const __hip_bfloat16* __restrict__ qkv,
    const __hip_bfloat16* __restrict__ vtg,
    __hip_bfloat16* __restrict__ outb)
{
    const int i   = blockIdx.x;   // q block
    const int h   = blockIdx.y;
    const int b   = blockIdx.z;
    const int kvh = h >> 2;
    const int tid  = threadIdx.x;
    const int lane = tid & 63;
    const int w    = tid >> 6;
    const int m16  = lane & 15;
    const int q8   = lane >> 4;

    __shared__ __align__(16) __hip_bfloat16 Ks[64 * 136];   // K rows padded +8
    __shared__ __align__(16) __hip_bfloat16 VT[128 * 72];   // V^T rows padded +8
    __shared__ __align__(16) __hip_bfloat16 Pb[4][16 * 72]; // per-wave P scratch

    // Q fragments (A-layout): row = lane&15 (+w*16), k-chunk = (lane>>4)*8
    bf16x8 qf[4];
    {
        const __hip_bfloat16* qp =
            qkv + (size_t)(b * Tlen + i * BLKQ + w * 16 + m16) * QKVC + h * Dh + q8 * 8;
        for (int ks = 0; ks < 4; ++ks) qf[ks] = *(const bf16x8*)(qp + ks * 32);
    }

    f32x4 o[8] = {};
    float mrow[4] = {-1e30f, -1e30f, -1e30f, -1e30f};
    float lrow[4] = {0.f, 0.f, 0.f, 0.f};

    const int nsel = (i + 1 < 9) ? (i + 1) : 9;
    auto kb_of = [&](int j) { return (i <= 7) ? j : ((j == 0) ? 0 : (i - 8 + j)); };

    const __hip_bfloat16* vtbase = vtg + (size_t)(b * HKV + kvh) * Dh * Tlen;

    // Prefetch tile 0 into registers.
    bf16x8 kr[4], vr[4];
    {
        const int kb0 = kb_of(0);
        const __hip_bfloat16* kbase =
            qkv + (size_t)(b * Tlen + kb0 * BLKQ) * QKVC + HID + kvh * Dh;
        #pragma unroll
        for (int t = 0; t < 4; ++t) {
            const int c = tid + t * 256;
            kr[t] = *(const bf16x8*)(kbase + (size_t)(c >> 4) * QKVC + (c & 15) * 8);
            vr[t] = *(const bf16x8*)(vtbase + (size_t)(c >> 3) * Tlen
                                     + kb0 * BLKQ + (c & 7) * 8);
        }
    }

    for (int j = 0; j < nsel; ++j) {
        const int kb = kb_of(j);

        __syncthreads();  // prev iter's LDS reads (Ks/VT/Pb) complete
        // K: row-major vector writes (b128, conflict-free)
        #pragma unroll
        for (int t = 0; t < 4; ++t) {
            const int c = tid + t * 256;
            *(bf16x8*)&Ks[(c >> 4) * 136 + (c & 15) * 8] = kr[t];
        }
        // V^T: vector writes from VTg rows (b128; 144 B row stride, aligned)
        #pragma unroll
        for (int t = 0; t < 4; ++t) {
            const int c = tid + t * 256;
            *(bf16x8*)&VT[(c >> 3) * 72 + (c & 7) * 8] = vr[t];
        }
        __syncthreads();  // staging visible

        // T14: issue next tile's loads now; consumed after next barrier.
        if (j + 1 < nsel) {
            const int kbn = kb_of(j + 1);
            const __hip_bfloat16* kbase =
                qkv + (size_t)(b * Tlen + kbn * BLKQ) * QKVC + HID + kvh * Dh;
            #pragma unroll
            for (int t = 0; t < 4; ++t) {
                const int c = tid + t * 256;
                kr[t] = *(const bf16x8*)(kbase + (size_t)(c >> 4) * QKVC + (c & 15) * 8);
                vr[t] = *(const bf16x8*)(vtbase + (size_t)(c >> 3) * Tlen
                                         + kbn * BLKQ + (c & 7) * 8);
            }
        }

        // S = Q K^T * scale  (16 q-rows x 64 keys per wave)
        float sv[4][4];
        __builtin_amdgcn_s_setprio(1);
        for (int nt = 0; nt < 4; ++nt) {
            f32x4 s = {0.f, 0.f, 0.f, 0.f};
            for (int ks = 0; ks < 4; ++ks) {
                bf16x8 kf = *(const bf16x8*)&Ks[(nt * 16 + m16) * 136 + ks * 32 + q8 * 8];
                s = MFMA16(qf[ks], kf, s);
            }
            for (int r = 0; r < 4; ++r) sv[nt][r] = s[r] * SCALE_C;
        }
        __builtin_amdgcn_s_setprio(0);
        if (kb == i) {  // causal mask on self block
            for (int nt = 0; nt < 4; ++nt) {
                const int key = nt * 16 + m16;
                for (int r = 0; r < 4; ++r) {
                    const int qr = w * 16 + q8 * 4 + r;
                    if (key > qr) sv[nt][r] = -1e9f;
                }
            }
        }

        // online softmax update (per row r; stats across 16 col-lanes)
        float alpha[4];
        for (int r = 0; r < 4; ++r) {
            float mx = fmaxf(fmaxf(sv[0][r], sv[1][r]), fmaxf(sv[2][r], sv[3][r]));
            for (int off = 1; off < 16; off <<= 1) mx = fmaxf(mx, __shfl_xor(mx, off, 64));
            const float newm = fmaxf(mrow[r], mx);
            alpha[r] = __expf(mrow[r] - newm);
            mrow[r] = newm;
            float rs = 0.f;
            for (int nt = 0; nt < 4; ++nt) {
                const float p = __expf(sv[nt][r] - newm);
                sv[nt][r] = p;
                rs += p;
            }
            for (int off = 1; off < 16; off <<= 1) rs += __shfl_xor(rs, off, 64);
            lrow[r] = lrow[r] * alpha[r] + rs;
        }

        // P: C-layout -> per-wave LDS -> A-layout (wave-local ordering only)
        __hip_bfloat16* Pw = &Pb[w][0];
        for (int nt = 0; nt < 4; ++nt)
            for (int r = 0; r < 4; ++r)
                Pw[(q8 * 4 + r) * 72 + nt * 16 + m16] = __float2bfloat16(sv[nt][r]);

        for (int dt = 0; dt < 8; ++dt)
            for (int r = 0; r < 4; ++r)
                o[dt][r] *= alpha[r];

        // P writes and reads are same-wave (Pb[w]): drain DS queue, pin order.
        asm volatile("s_waitcnt lgkmcnt(0)" ::: "memory");
        __builtin_amdgcn_sched_barrier(0);

        // O += P V  (k-dim = 64 keys, 2 k-steps; 8 d-tiles)
        __builtin_amdgcn_s_setprio(1);
        for (int kk = 0; kk < 2; ++kk) {
            bf16x8 pf = *(const bf16x8*)&Pw[m16 * 72 + kk * 32 + q8 * 8];
            for (int dt = 0; dt < 8; ++dt) {
                bf16x8 vf = *(const bf16x8*)&VT[(dt * 16 + m16) * 72 + kk * 32 + q8 * 8];
                o[dt] = MFMA16(pf, vf, o[dt]);
            }
        }
        __builtin_amdgcn_s_setprio(0);
    }

    // epilogue: O * (1/l) -> attn buffer [B*T][H*D] (bf16)
    float rcp[4];
    for (int r = 0; r < 4; ++r) rcp[r] = 1.0f / lrow[r];
    __hip_bfloat16* op = outb + (size_t)(b * Tlen + i * BLKQ) * (Hq * Dh) + h * Dh;
    for (int dt = 0; dt < 8; ++dt)
        for (int r = 0; r < 4; ++r) {
            const float val = o[dt][r] * rcp[r];
            op[(size_t)(w * 16 + q8 * 4 + r) * (Hq * Dh) + dt * 16 + m16] =
                __float2bfloat16(val);
        }
}

extern "C" void kernel_launch(void* const* d_in, const int* in_sizes, int n_in,
                              void* d_out, int out_size, void* d_ws, size_t ws_size,
                              hipStream_t stream) {
    const float* hs   = (const float*)d_in[0];
    const float* cosb = (const float*)d_in[1];
    const float* sinb = (const float*)d_in[2];
    const float* Wq   = (const float*)d_in[3];
    const float* Wk   = (const float*)d_in[4];
    const float* Wv   = (const float*)d_in[5];
    const float* Wo   = (const float*)d_in[6];

    const int M = Bsz * Tlen;                 // 8192
    const int nHS = M * HID;
    const int nWq = Hq * Dh * HID;
    const int nWk = HKV * Dh * HID;
    const int nWv = nWk;
    const int nWo = HID * Hq * Dh;

    // ws layout (bf16): hs | Wq | Wk | Wv | Wo | qkv | attn | vtg
    __hip_bfloat16* hsb  = (__hip_bfloat16*)d_ws;
    __hip_bfloat16* wqb  = hsb + nHS;
    __hip_bfloat16* wkb  = wqb + nWq;
    __hip_bfloat16* wvb  = wkb + nWk;
    __hip_bfloat16* wob  = wvb + nWv;
    __hip_bfloat16* qkv  = wob + nWo;               // [8192][3072]
    __hip_bfloat16* attn = qkv + (size_t)M * QKVC;  // [8192][2048]
    __hip_bfloat16* vtg  = attn + (size_t)M * (Hq * Dh);  // [8][128][4096]

    // 0) f32 -> bf16 conversion of hs + all weights
    cvt_kernel<<<dim3(8192, 5), 256, 0, stream>>>(
        hs, Wq, Wk, Wv, Wo, hsb, nHS, nWq, nWk, nWv, nWo);
    // 1) fused QKV projection + RoPE epilogue (bf16 out), 128sq eager-stage
    gemm128db<true, false><<<dim3(QKVC / 128, M / 128), 256, 0, stream>>>(
        hsb, wqb, wkb, wvb, HID, HID + 512, qkv, M, QKVC, HID, cosb, sinb);
    // 2) V pre-transpose for attention
    vtrans_kernel<<<dim3(NBLK, Bsz * HKV), 256, 0, stream>>>(qkv, vtg);
    // 3) block-sparse attention (bf16)
    attn_kernel<<<dim3(NBLK, Hq, Bsz), 256, 0, stream>>>(qkv, vtg, attn);
    // 4) output projection (f32 out to d_out), 128sq eager-stage
    gemm128db<false, true><<<dim3(HID / 128, M / 128), 256, 0, stream>>>(
        attn, wob, wob, wob, HID, HID, d_out, M, HID, HID, nullptr, nullptr);
}

// Round 6
// 413.622 us; speedup vs baseline: 1.1915x; 1.0052x over previous
//
#include <hip/hip_runtime.h>
#include <hip/hip_bf16.h>

// Problem constants (HumanVAttention: B=2,T=4096,HID=2048,H=16,HKV=4,D=128,
// ROT=64, BLK=64, LOCAL=8, GLOB=1).
// DTYPE (established empirically): harness presents ALL tensors in f32.
// Internal compute bf16 MFMA; I/O f32. Threshold is bf16-grade.
#define Hq   16
#define HKV  4
#define Dh   128
#define ROT  64
#define BLKQ 64
#define NBLK 64      // T/BLK
#define Tlen 4096
#define Bsz  2
#define HID  2048
#define QKVC 3072    // 2048 q + 512 k + 512 v
#define SCALE_C 0.08838834764831845f

typedef __attribute__((ext_vector_type(8))) short bf16x8;
typedef __attribute__((ext_vector_type(4))) float f32x4;
typedef __attribute__((ext_vector_type(4))) unsigned short u16x4;

#define MFMA16(a, b, c) __builtin_amdgcn_mfma_f32_16x16x32_bf16((a), (b), (c), 0, 0, 0)

__device__ __forceinline__ void async_copy16(__hip_bfloat16* lds, const __hip_bfloat16* g) {
    __builtin_amdgcn_global_load_lds(
        (const __attribute__((address_space(1))) void*)g,
        (__attribute__((address_space(3))) void*)lds,
        16, 0, 0);
}

// f32 -> bf16 bulk convert. blockIdx.y selects tensor {hs, Wq, Wk, Wv, Wo}.
__global__ __launch_bounds__(256) void cvt_kernel(
    const float* __restrict__ s0, const float* __restrict__ s1,
    const float* __restrict__ s2, const float* __restrict__ s3,
    const float* __restrict__ s4,
    __hip_bfloat16* __restrict__ base,
    int n0, int n1, int n2, int n3, int n4)
{
    const float* src;
    size_t off, n;
    switch (blockIdx.y) {
        case 0:  src = s0; off = 0;                          n = n0; break;
        case 1:  src = s1; off = (size_t)n0;                 n = n1; break;
        case 2:  src = s2; off = (size_t)n0 + n1;            n = n2; break;
        case 3:  src = s3; off = (size_t)n0 + n1 + n2;       n = n3; break;
        default: src = s4; off = (size_t)n0 + n1 + n2 + n3;  n = n4; break;
    }
    __hip_bfloat16* dst = base + off;
    const size_t stride = (size_t)gridDim.x * 2048;
    for (size_t i = ((size_t)blockIdx.x * 256 + threadIdx.x) * 8; i < n; i += stride) {
        const float4 a = *(const float4*)(src + i);
        const float4 b = *(const float4*)(src + i + 4);
        union { bf16x8 v; __hip_bfloat16 e[8]; } u;
        u.e[0] = __float2bfloat16(a.x); u.e[1] = __float2bfloat16(a.y);
        u.e[2] = __float2bfloat16(a.z); u.e[3] = __float2bfloat16(a.w);
        u.e[4] = __float2bfloat16(b.x); u.e[5] = __float2bfloat16(b.y);
        u.e[6] = __float2bfloat16(b.z); u.e[7] = __float2bfloat16(b.w);
        *(bf16x8*)(dst + i) = u.v;
    }
}

// C[M,N] = A[M,K] * B[N,K]^T, bf16 in. 128x128 tile, BK=64, 4 waves, 256 thr,
// double-buffered 64 KiB LDS => 2 independent blocks/CU. Eager-stage: tile u
// stages tile u+2 into buf[P] (the buffer tile u just read) after bar1
// certifies all reads are in registers; vmcnt(8) at the boundary waits on
// loads issued two tiles ago (never drains to 0 in the main loop).
// R4 measured: MfmaUtil 44%, LDS-pipe ~54% -> the two pipes saturate the CU.
template <bool ROPE_, bool F32OUT>
__global__ __launch_bounds__(256, 2) void gemm128db(
    const __hip_bfloat16* __restrict__ A,
    const __hip_bfloat16* __restrict__ B0,
    const __hip_bfloat16* __restrict__ B1,
    const __hip_bfloat16* __restrict__ B2,
    int n1c, int n2c,
    void* __restrict__ C,
    int M, int N, int K,
    const float* __restrict__ cosb,
    const float* __restrict__ sinb)
{
    __shared__ __align__(16) __hip_bfloat16 As[2][128 * 64];
    __shared__ __align__(16) __hip_bfloat16 Bs[2][128 * 64];

    const int m0 = blockIdx.y * 128;
    const int n0 = blockIdx.x * 128;
    const __hip_bfloat16* Bp;
    int nb;
    if (n0 < n1c)      { Bp = B0; nb = n0; }
    else if (n0 < n2c) { Bp = B1; nb = n0 - n1c; }
    else               { Bp = B2; nb = n0 - n2c; }

    const int tid  = threadIdx.x;
    const int lane = tid & 63;
    const int w    = tid >> 6;          // wave 0..3
    const int wm   = (w >> 1) * 64;
    const int wn   = (w & 1) * 64;
    const int lr   = lane >> 3;         // row within 8-row staging group
    const int lc   = lane & 7;          // chunk slot
    const int m16  = lane & 15;
    const int q8   = lane >> 4;
    const int NT   = K >> 6;            // 32 here (>= 3 assumed)

    f32x4 acc[4][4] = {};

    auto stageA = [&](int buf, int kc) {
        #pragma unroll
        for (int ii = 0; ii < 4; ++ii) {
            const int r8 = w * 32 + ii * 8;
            const int r  = r8 + lr;
            const int cg = lc ^ (r & 7);
            async_copy16(&As[buf][r8 * 64], A + (size_t)(m0 + r) * K + kc + cg * 8);
        }
    };
    auto stageB = [&](int buf, int kc) {
        #pragma unroll
        for (int ii = 0; ii < 4; ++ii) {
            const int r8 = w * 32 + ii * 8;
            const int r  = r8 + lr;
            const int cg = lc ^ (r & 7);
            async_copy16(&Bs[buf][r8 * 64], Bp + (size_t)(nb + r) * K + kc + cg * 8);
        }
    };

    // Prologue: tile0 -> buf0 (8 loads/thread), tile1 -> buf1 (8 loads).
    // vmcnt(8) = tile0 complete, tile1 may still fly.
    stageA(0, 0);
    stageB(0, 0);
    stageA(1, 64);
    stageB(1, 64);
    asm volatile("s_waitcnt vmcnt(8)" ::: "memory");
    __builtin_amdgcn_s_barrier();

    for (int u = 0; u < NT; ++u) {
        const int P  = u & 1;
        const __hip_bfloat16* Ap_ = As[P];
        const __hip_bfloat16* Bq_ = Bs[P];

        // All 16 fragment reads of tile u (k0: cs=q8, k1: cs=4+q8).
        bf16x8 a0[4], b0[4], a1[4], b1[4];
        #pragma unroll
        for (int t = 0; t < 4; ++t) {
            const int row = wm + t * 16 + m16;
            const int col = wn + t * 16 + m16;
            a0[t] = *(const bf16x8*)&Ap_[row * 64 + ((q8)     ^ (row & 7)) * 8];
            b0[t] = *(const bf16x8*)&Bq_[col * 64 + ((q8)     ^ (col & 7)) * 8];
            a1[t] = *(const bf16x8*)&Ap_[row * 64 + ((4 + q8) ^ (row & 7)) * 8];
            b1[t] = *(const bf16x8*)&Bq_[col * 64 + ((4 + q8) ^ (col & 7)) * 8];
        }
        // Per-wave drain: all reads of buf[P] now in registers.
        asm volatile("s_waitcnt lgkmcnt(0)" ::: "memory");
        __builtin_amdgcn_sched_barrier(0);
        __builtin_amdgcn_s_barrier();            // bar1: whole block done reading buf[P]
        __builtin_amdgcn_sched_barrier(0);       // keep stages below bar1

        if (u + 2 < NT) {                        // eager-stage tile u+2 -> buf[P]
            stageA(P, (u + 2) << 6);
            stageB(P, (u + 2) << 6);
        }

        __builtin_amdgcn_s_setprio(1);
        #pragma unroll
        for (int i = 0; i < 4; ++i)
            #pragma unroll
            for (int j = 0; j < 4; ++j)
                acc[i][j] = MFMA16(a0[i], b0[j], acc[i][j]);
        #pragma unroll
        for (int i = 0; i < 4; ++i)
            #pragma unroll
            for (int j = 0; j < 4; ++j)
                acc[i][j] = MFMA16(a1[i], b1[j], acc[i][j]);
        __builtin_amdgcn_s_setprio(0);

        // Tile boundary: need tile u+1 (issued two tiles ago) complete.
        if (u + 2 < NT) {
            asm volatile("s_waitcnt vmcnt(8)" ::: "memory");
        } else {
            asm volatile("s_waitcnt vmcnt(0)" ::: "memory");
        }
        __builtin_amdgcn_s_barrier();            // bar2: buf[P^1] ready for tile u+1
    }

    // Fused RoPE: q/k head tiles (n0 < n2c == 2560), rot half (wn == 0).
    if (ROPE_ && n0 < n2c && wn == 0) {
        #pragma unroll
        for (int i = 0; i < 4; ++i)
            #pragma unroll
            for (int r = 0; r < 4; ++r) {
                const int bt = m0 + wm + i * 16 + q8 * 4 + r;   // b*T + t
                #pragma unroll
                for (int j = 0; j < 2; ++j) {
                    const int d = j * 16 + m16;
                    const float c = cosb[(size_t)bt * ROT + d];
                    const float s = sinb[(size_t)bt * ROT + d];
                    const float x1 = acc[i][j][r];
                    const float x2 = acc[i][j + 2][r];
                    acc[i][j][r]     = x1 * c - x2 * s;
                    acc[i][j + 2][r] = x2 * c + x1 * s;
                }
            }
    }

    // epilogue: C layout col=lane&15, row=(lane>>4)*4+reg
    #pragma unroll
    for (int i = 0; i < 4; ++i)
        #pragma unroll
        for (int j = 0; j < 4; ++j)
            #pragma unroll
            for (int r = 0; r < 4; ++r) {
                const int row = m0 + wm + i * 16 + q8 * 4 + r;
                const int col = n0 + wn + j * 16 + m16;
                if (F32OUT)
                    ((float*)C)[(size_t)row * N + col] = acc[i][j][r];
                else
                    ((__hip_bfloat16*)C)[(size_t)row * N + col] =
                        __float2bfloat16(acc[i][j][r]);
            }
}

// V pre-transpose: qkv V block [b][t][kvh][d] -> VTg[(b*4+kvh)*128 + d][t]
// (d-major, bf16). Done ONCE so attn stages V^T with vector writes.
__global__ __launch_bounds__(256) void vtrans_kernel(
    const __hip_bfloat16* __restrict__ qkv,
    __hip_bfloat16* __restrict__ vtg)
{
    const int tb = blockIdx.x;   // t block of 64 (0..63)
    const int pr = blockIdx.y;   // b*4 + kvh (0..7)
    const __hip_bfloat16* src =
        qkv + ((size_t)(pr >> 2) * Tlen + tb * 64) * QKVC + HID + 512 + (pr & 3) * Dh;
    __hip_bfloat16* dst = vtg + (size_t)pr * Dh * Tlen + tb * 64;
    const int tid = threadIdx.x;
    #pragma unroll
    for (int t2 = 0; t2 < 4; ++t2) {
        const int c  = tid + t2 * 256;   // 0..1023: d = c>>3, t0 = (c&7)*8
        const int d  = c >> 3;
        const int t0 = (c & 7) * 8;
        union { bf16x8 v; __hip_bfloat16 e[8]; } u;
        #pragma unroll
        for (int j = 0; j < 8; ++j)
            u.e[j] = src[(size_t)(t0 + j) * QKVC + d];
        *(bf16x8*)(dst + (size_t)d * Tlen + t0) = u.v;
    }
}

// Block-sparse flash attention. Grid (qblock=64, head=16, batch=2), 256 thr.
//
// Swapped QK^T + in-register softmax (R5 structure, R6 MASK FIX):
// S^T = mfma(K, Q) — zero-cost because 16x16x32 A-frag and B-frag per-lane
// addressing coincide. Lane owns q-row (w*16 + m16) with 16 S values in regs
// (keys nt*16 + q8*4 + r):
//  - row max/sum: in-register tree + 2 shfl_xor (16,32)   [was 32 shfl]
//  - P: 4 consecutive keys per nt -> one b64 write        [was 16 b16]
//  - PV swapped: O^T = mfma(V^T, P); epilogue packs 4 d-values into 8B stores
//  - VT/Pb: stride 64 + XOR chunk swizzle on write AND read -> conflict-free
// R6 FIX: self-block causal mask is key > W*16+m16, NOT key > m16 — the
// "w part cancels" claim was wrong (waves 1-3 over-masked; absmax 3.2).
__global__ __launch_bounds__(256, 3) void attn_kernel(
    const __hip_bfloat16* __restrict__ qkv,
    const __hip_bfloat16* __restrict__ vtg,
    __hip_bfloat16* __restrict__ outb)
{
    const int i   = blockIdx.x;   // q block
    const int h   = blockIdx.y;
    const int b   = blockIdx.z;
    const int kvh = h >> 2;
    const int tid  = threadIdx.x;
    const int lane = tid & 63;
    const int w    = tid >> 6;
    const int m16  = lane & 15;
    const int q8   = lane >> 4;

    __shared__ __align__(16) __hip_bfloat16 Ks[64 * 136];   // K rows, 272B stride
    __shared__ __align__(16) __hip_bfloat16 VT[128 * 64];   // V^T, XOR-swizzled chunks
    __shared__ __align__(16) __hip_bfloat16 Pb[4][16 * 64]; // per-wave P, XOR-swizzled

    // Q fragments: row = lane&15 (+w*16), k-chunk = (lane>>4)*8 (B-frag now)
    bf16x8 qf[4];
    {
        const __hip_bfloat16* qp =
            qkv + (size_t)(b * Tlen + i * BLKQ + w * 16 + m16) * QKVC + h * Dh + q8 * 8;
        for (int ks = 0; ks < 4; ++ks) qf[ks] = *(const bf16x8*)(qp + ks * 32);
    }

    f32x4 o[8] = {};                 // O^T: o[dt][r] = O[m16][dt*16+q8*4+r]
    float mrow = -1e30f, lrow = 0.f; // per-lane scalars (lane's q-row = w*16+m16)

    const int nsel = (i + 1 < 9) ? (i + 1) : 9;
    auto kb_of = [&](int j) { return (i <= 7) ? j : ((j == 0) ? 0 : (i - 8 + j)); };

    const __hip_bfloat16* vtbase = vtg + (size_t)(b * HKV + kvh) * Dh * Tlen;

    // Prefetch tile 0 into registers.
    bf16x8 kr[4], vr[4];
    {
        const int kb0 = kb_of(0);
        const __hip_bfloat16* kbase =
            qkv + (size_t)(b * Tlen + kb0 * BLKQ) * QKVC + HID + kvh * Dh;
        #pragma unroll
        for (int t = 0; t < 4; ++t) {
            const int c = tid + t * 256;
            kr[t] = *(const bf16x8*)(kbase + (size_t)(c >> 4) * QKVC + (c & 15) * 8);
            vr[t] = *(const bf16x8*)(vtbase + (size_t)(c >> 3) * Tlen
                                     + kb0 * BLKQ + (c & 7) * 8);
        }
    }

    for (int j = 0; j < nsel; ++j) {
        const int kb = kb_of(j);

        __syncthreads();  // prev iter's LDS reads (Ks/VT/Pb) complete
        // K: row-major vector writes (b128)
        #pragma unroll
        for (int t = 0; t < 4; ++t) {
            const int c = tid + t * 256;
            *(bf16x8*)&Ks[(c >> 4) * 136 + (c & 15) * 8] = kr[t];
        }
        // V^T: vector writes, XOR chunk swizzle (phys chunk = (c&7) ^ (row&7))
        #pragma unroll
        for (int t = 0; t < 4; ++t) {
            const int c = tid + t * 256;
            const int row = c >> 3;
            *(bf16x8*)&VT[row * 64 + (((c & 7) ^ (row & 7)) << 3)] = vr[t];
        }
        __syncthreads();  // staging visible

        // T14: issue next tile's loads now; consumed after next barrier.
        if (j + 1 < nsel) {
            const int kbn = kb_of(j + 1);
            const __hip_bfloat16* kbase =
                qkv + (size_t)(b * Tlen + kbn * BLKQ) * QKVC + HID + kvh * Dh;
            #pragma unroll
            for (int t = 0; t < 4; ++t) {
                const int c = tid + t * 256;
                kr[t] = *(const bf16x8*)(kbase + (size_t)(c >> 4) * QKVC + (c & 15) * 8);
                vr[t] = *(const bf16x8*)(vtbase + (size_t)(c >> 3) * Tlen
                                         + kbn * BLKQ + (c & 7) * 8);
            }
        }

        // S^T = (Q K^T)^T * scale: mfma(A=K, B=Q). Lane holds S[key][qrow]
        // for key = nt*16 + q8*4 + r, qrow = w*16 + m16.
        float sv[4][4];
        __builtin_amdgcn_s_setprio(1);
        for (int nt = 0; nt < 4; ++nt) {
            f32x4 s = {0.f, 0.f, 0.f, 0.f};
            for (int ks = 0; ks < 4; ++ks) {
                bf16x8 kf = *(const bf16x8*)&Ks[(nt * 16 + m16) * 136 + ks * 32 + q8 * 8];
                s = MFMA16(kf, qf[ks], s);
            }
            for (int r = 0; r < 4; ++r) sv[nt][r] = s[r] * SCALE_C;
        }
        __builtin_amdgcn_s_setprio(0);
        if (kb == i) {  // causal mask on self block: key > q-row-in-block
            const int qr = w * 16 + m16;   // R6 FIX: w*16 is REQUIRED
            #pragma unroll
            for (int nt = 0; nt < 4; ++nt)
                #pragma unroll
                for (int r = 0; r < 4; ++r)
                    if (nt * 16 + q8 * 4 + r > qr) sv[nt][r] = -1e9f;
        }

        // online softmax: in-register 16-way reduce + 2 shfl_xor across q8 dups
        float mx = sv[0][0];
        #pragma unroll
        for (int nt = 0; nt < 4; ++nt)
            #pragma unroll
            for (int r = 0; r < 4; ++r) mx = fmaxf(mx, sv[nt][r]);
        mx = fmaxf(mx, __shfl_xor(mx, 16, 64));
        mx = fmaxf(mx, __shfl_xor(mx, 32, 64));
        const float newm = fmaxf(mrow, mx);
        const float alpha = __expf(mrow - newm);
        mrow = newm;
        float rs = 0.f;
        #pragma unroll
        for (int nt = 0; nt < 4; ++nt)
            #pragma unroll
            for (int r = 0; r < 4; ++r) {
                const float p = __expf(sv[nt][r] - newm);
                sv[nt][r] = p;
                rs += p;
            }
        rs += __shfl_xor(rs, 16, 64);
        rs += __shfl_xor(rs, 32, 64);
        lrow = lrow * alpha + rs;

        // P: per nt, 4 consecutive keys -> one b64 write (XOR-swizzled).
        __hip_bfloat16* Pw = &Pb[w][0];
        #pragma unroll
        for (int nt = 0; nt < 4; ++nt) {
            union { u16x4 v; __hip_bfloat16 e[4]; } u;
            u.e[0] = __float2bfloat16(sv[nt][0]);
            u.e[1] = __float2bfloat16(sv[nt][1]);
            u.e[2] = __float2bfloat16(sv[nt][2]);
            u.e[3] = __float2bfloat16(sv[nt][3]);
            const int chunk = (nt * 2 + (q8 >> 1)) ^ (m16 & 7);
            *(u16x4*)&Pw[m16 * 64 + (chunk << 3) + ((q8 & 1) << 2)] = u.v;
        }

        #pragma unroll
        for (int dt = 0; dt < 8; ++dt)
            #pragma unroll
            for (int r = 0; r < 4; ++r)
                o[dt][r] *= alpha;

        // P writes/reads are same-wave (Pb[w]): drain DS queue, pin order.
        asm volatile("s_waitcnt lgkmcnt(0)" ::: "memory");
        __builtin_amdgcn_sched_barrier(0);

        // O^T += V^T P^T : mfma(A=V^T, B=P); k = 64 keys, 2 k-steps; 8 d-tiles
        __builtin_amdgcn_s_setprio(1);
        for (int kk = 0; kk < 2; ++kk) {
            const int co = ((kk * 4 + q8) ^ (m16 & 7)) << 3;   // swizzled chunk
            bf16x8 pf = *(const bf16x8*)&Pw[m16 * 64 + co];
            #pragma unroll
            for (int dt = 0; dt < 8; ++dt) {
                bf16x8 vf = *(const bf16x8*)&VT[(dt * 16 + m16) * 64 + co];
                o[dt] = MFMA16(vf, pf, o[dt]);
            }
        }
        __builtin_amdgcn_s_setprio(0);
    }

    // epilogue: O^T * (1/l) -> attn buffer [B*T][H*D] (bf16), 8B stores
    const float rcp = 1.0f / lrow;
    __hip_bfloat16* op = outb + (size_t)(b * Tlen + i * BLKQ + w * 16 + m16) * (Hq * Dh)
                        + h * Dh + q8 * 4;
    #pragma unroll
    for (int dt = 0; dt < 8; ++dt) {
        union { u16x4 v; __hip_bfloat16 e[4]; } u;
        #pragma unroll
        for (int r = 0; r < 4; ++r)
            u.e[r] = __float2bfloat16(o[dt][r] * rcp);
        *(u16x4*)(op + dt * 16) = u.v;
    }
}

extern "C" void kernel_launch(void* const* d_in, const int* in_sizes, int n_in,
                              void* d_out, int out_size, void* d_ws, size_t ws_size,
                              hipStream_t stream) {
    const float* hs   = (const float*)d_in[0];
    const float* cosb = (const float*)d_in[1];
    const float* sinb = (const float*)d_in[2];
    const float* Wq   = (const float*)d_in[3];
    const float* Wk   = (const float*)d_in[4];
    const float* Wv   = (const float*)d_in[5];
    const float* Wo   = (const float*)d_in[6];

    const int M = Bsz * Tlen;                 // 8192
    const int nHS = M * HID;
    const int nWq = Hq * Dh * HID;
    const int nWk = HKV * Dh * HID;
    const int nWv = nWk;
    const int nWo = HID * Hq * Dh;

    // ws layout (bf16): hs | Wq | Wk | Wv | Wo | qkv | attn | vtg
    __hip_bfloat16* hsb  = (__hip_bfloat16*)d_ws;
    __hip_bfloat16* wqb  = hsb + nHS;
    __hip_bfloat16* wkb  = wqb + nWq;
    __hip_bfloat16* wvb  = wkb + nWk;
    __hip_bfloat16* wob  = wvb + nWv;
    __hip_bfloat16* qkv  = wob + nWo;               // [8192][3072]
    __hip_bfloat16* attn = qkv + (size_t)M * QKVC;  // [8192][2048]
    __hip_bfloat16* vtg  = attn + (size_t)M * (Hq * Dh);  // [8][128][4096]

    // 0) f32 -> bf16 conversion of hs + all weights
    cvt_kernel<<<dim3(8192, 5), 256, 0, stream>>>(
        hs, Wq, Wk, Wv, Wo, hsb, nHS, nWq, nWk, nWv, nWo);
    // 1) fused QKV projection + RoPE epilogue (bf16 out), 128sq eager-stage
    gemm128db<true, false><<<dim3(QKVC / 128, M / 128), 256, 0, stream>>>(
        hsb, wqb, wkb, wvb, HID, HID + 512, qkv, M, QKVC, HID, cosb, sinb);
    // 2) V pre-transpose for attention
    vtrans_kernel<<<dim3(NBLK, Bsz * HKV), 256, 0, stream>>>(qkv, vtg);
    // 3) block-sparse attention (bf16, swapped-QK in-register softmax)
    attn_kernel<<<dim3(NBLK, Hq, Bsz), 256, 0, stream>>>(qkv, vtg, attn);
    // 4) output projection (f32 out to d_out), 128sq eager-stage
    gemm128db<false, true><<<dim3(HID / 128, M / 128), 256, 0, stream>>>(
        attn, wob, wob, wob, HID, HID, d_out, M, HID, HID, nullptr, nullptr);
}